// Round 1
// baseline (814.044 us; speedup 1.0000x reference)
//
#include <hip/hip_runtime.h>
#include <stdint.h>

#define B_ 4
#define T_ 2048
#define D_ 2048
#define H_ 16
#define HD_ 128
#define I_ 5632
#define K_ 512
#define S_ 2048
#define D3_ (3 * D_)

typedef float f32x4 __attribute__((ext_vector_type(4)));
typedef short s16x8 __attribute__((ext_vector_type(8)));
typedef __bf16 bf16x8 __attribute__((ext_vector_type(8)));

// ---------- mfma wrapper robust to builtin operand type (short8 vs bf16x8) ----------
template <typename V>
__device__ __forceinline__ auto mfma_try(V a, V b, f32x4 c, int)
    -> decltype(__builtin_amdgcn_mfma_f32_16x16x32_bf16(a, b, c, 0, 0, 0)) {
  return __builtin_amdgcn_mfma_f32_16x16x32_bf16(a, b, c, 0, 0, 0);
}
template <typename V>
__device__ __forceinline__ f32x4 mfma_try(V a, V b, f32x4 c, long) {
  return __builtin_amdgcn_mfma_f32_16x16x32_bf16(
      __builtin_bit_cast(bf16x8, a), __builtin_bit_cast(bf16x8, b), c, 0, 0, 0);
}
__device__ __forceinline__ f32x4 mfma_bf16(s16x8 a, s16x8 b, f32x4 c) {
  return mfma_try(a, b, c, 0);
}

__device__ __forceinline__ void gl_lds16(const void* g, void* l) {
  __builtin_amdgcn_global_load_lds((const __attribute__((address_space(1))) void*)g,
                                   (__attribute__((address_space(3))) void*)l, 16, 0, 0);
}

__device__ __forceinline__ unsigned short f2bf(float f) {
  unsigned u = __float_as_uint(f);
  u += 0x7FFFu + ((u >> 16) & 1);
  return (unsigned short)(u >> 16);
}
__device__ __forceinline__ float bf2f(unsigned short s) {
  return __uint_as_float(((unsigned)s) << 16);
}

// ---------- K1: copy hidden -> out ----------
__global__ __launch_bounds__(256) void k_copy(const float4* __restrict__ src,
                                              float4* __restrict__ dst, int n4) {
  int i = blockIdx.x * 256 + threadIdx.x;
  int stride = gridDim.x * 256;
  for (; i < n4; i += stride) dst[i] = src[i];
}

// ---------- K2: router scores ----------
__global__ __launch_bounds__(256) void k_scores(const float* __restrict__ hid,
                                                const float* __restrict__ rw,
                                                const float* __restrict__ rb,
                                                float* __restrict__ scores) {
  int row = blockIdx.x * 4 + (threadIdx.x >> 6);
  int lane = threadIdx.x & 63;
  const float* hr = hid + (size_t)row * D_;
  float acc = 0.f;
  for (int i = lane; i < D_; i += 64) acc += hr[i] * rw[i];
#pragma unroll
  for (int d = 32; d; d >>= 1) acc += __shfl_xor(acc, d);
  if (lane == 0) scores[row] = acc + rb[0];
}

// ---------- K3: exact top-k (bitonic, matches jax.lax.top_k tie-break) ----------
__global__ __launch_bounds__(1024) void k_topk(const float* __restrict__ scores,
                                               int* __restrict__ pos) {
  __shared__ unsigned long long keys[T_];
  __shared__ int sidx[K_];
  int b = blockIdx.x, t = threadIdx.x;
  for (int i = t; i < T_; i += 1024) {
    unsigned u = __float_as_uint(scores[b * T_ + i]);
    u = (u & 0x80000000u) ? ~u : (u | 0x80000000u);
    keys[i] = ((unsigned long long)u << 32) | (unsigned)(~(unsigned)i);
  }
  __syncthreads();
  for (int k = 2; k <= T_; k <<= 1)
    for (int j = k >> 1; j > 0; j >>= 1) {
      for (int i = t; i < T_; i += 1024) {
        int l = i ^ j;
        if (l > i) {
          unsigned long long a = keys[i], c = keys[l];
          bool desc = ((i & k) == 0);
          if (desc ? (a < c) : (a > c)) { keys[i] = c; keys[l] = a; }
        }
      }
      __syncthreads();
    }
  if (t < K_) sidx[t] = (int)(~(unsigned)(keys[t] & 0xFFFFFFFFull));
  __syncthreads();
  for (int k = 2; k <= K_; k <<= 1)
    for (int j = k >> 1; j > 0; j >>= 1) {
      if (t < K_) {
        int i = t, l = i ^ j;
        if (l > i && l < K_) {
          int a = sidx[i], c = sidx[l];
          bool asc = ((i & k) == 0);
          if (asc ? (a > c) : (a < c)) { sidx[i] = c; sidx[l] = a; }
        }
      }
      __syncthreads();
    }
  if (t < K_) pos[b * K_ + t] = sidx[t];
}

// ---------- K4: gather + RMS1 + gate + rope tables ----------
__global__ __launch_bounds__(256) void k_gather(const float* __restrict__ hidden,
    const int* __restrict__ pos, const float* __restrict__ scores,
    const float* __restrict__ ln1w, float* __restrict__ x,
    unsigned short* __restrict__ xn, float* __restrict__ gate,
    float* __restrict__ cosb, float* __restrict__ sinb) {
  int s = blockIdx.x, t = threadIdx.x;
  int b = s >> 9, p = pos[s];
  const float* src = hidden + ((size_t)b * T_ + p) * D_;
  float v[8];
  float ss = 0.f;
#pragma unroll
  for (int i = 0; i < 8; i++) { v[i] = src[t + i * 256]; ss += v[i] * v[i]; }
  __shared__ float red[4];
#pragma unroll
  for (int d = 32; d; d >>= 1) ss += __shfl_xor(ss, d);
  if ((t & 63) == 0) red[t >> 6] = ss;
  __syncthreads();
  ss = red[0] + red[1] + red[2] + red[3];
  float scale = rsqrtf(ss / (float)D_ + 1e-6f);
  float* xd = x + (size_t)s * D_;
  unsigned short* xnd = xn + (size_t)s * D_;
#pragma unroll
  for (int i = 0; i < 8; i++) {
    int c = t + i * 256;
    xd[c] = v[i];
    xnd[c] = f2bf(v[i] * scale * ln1w[c]);
  }
  if (t == 0) gate[s] = 1.f / (1.f + expf(-scores[b * T_ + p]));
  if (t < 64) {
    float invf = powf(10000.0f, -(float)t / 64.0f);
    float f = (float)p * invf;
    cosb[s * 64 + t] = cosf(f);
    sinb[s * 64 + t] = sinf(f);
  }
}

// ---------- K5: transpose + f32->bf16 (weights to Bt layout) ----------
__global__ __launch_bounds__(256) void k_transpose(const float* __restrict__ src,
                                                   unsigned short* __restrict__ dst,
                                                   int R, int C) {
  __shared__ float tile[32][33];
  int tx = threadIdx.x & 31, ty = threadIdx.x >> 5;
  int c0 = blockIdx.x * 32, r0 = blockIdx.y * 32;
#pragma unroll
  for (int i = 0; i < 4; i++) {
    int r = ty + i * 8;
    tile[r][tx] = src[(size_t)(r0 + r) * C + c0 + tx];
  }
  __syncthreads();
#pragma unroll
  for (int i = 0; i < 4; i++) {
    int r = ty + i * 8;
    dst[(size_t)(c0 + r) * R + r0 + tx] = f2bf(tile[tx][r]);
  }
}

// ---------- GEMM building blocks (m97 structure: 128x128 tile, BK=32) ----------
__device__ __forceinline__ void stage_tile(const unsigned short* __restrict__ gbase,
                                           int ldK, int row0, int k0, char* lds, int tid) {
  int w = tid >> 6, lane = tid & 63;
#pragma unroll
  for (int p = 0; p < 2; p++) {
    int ldsoff = p * 4096 + w * 1024;
    int boff = ldsoff + lane * 16;
    int row = boff >> 6;
    int ke = (boff & 63) >> 1;
    gl_lds16(gbase + (size_t)(row0 + row) * ldK + k0 + ke, lds + ldsoff);
  }
}

__device__ __forceinline__ void gemm_step(const char* As, const char* Bs, int wr, int wc,
                                          int g, int lr, f32x4 acc[4][4]) {
  s16x8 af[4], bf4[4];
#pragma unroll
  for (int i = 0; i < 4; i++)
    af[i] = *(const s16x8*)(As + ((wr + i * 16 + lr) << 6) + (g << 4));
#pragma unroll
  for (int i = 0; i < 4; i++)
    bf4[i] = *(const s16x8*)(Bs + ((wc + i * 16 + lr) << 6) + (g << 4));
#pragma unroll
  for (int m = 0; m < 4; m++)
#pragma unroll
    for (int n = 0; n < 4; n++) acc[m][n] = mfma_bf16(af[m], bf4[n], acc[m][n]);
}

#define GEMM_PRE()                                                     \
  int tid = threadIdx.x;                                               \
  int w = tid >> 6, lane = tid & 63, g = lane >> 4, lr = lane & 15;    \
  int wr = (w >> 1) * 64, wc = (w & 1) * 64;                           \
  int m0 = blockIdx.x * 128, n0 = blockIdx.y * 128;                    \
  f32x4 zero4 = {0.f, 0.f, 0.f, 0.f};                                  \
  (void)lane;

// ---------- K6: fused QKV GEMM (bias epilogue) ----------
__global__ __launch_bounds__(256) void k_gemm_qkv(const unsigned short* __restrict__ A,
    const unsigned short* __restrict__ Bt, unsigned short* __restrict__ C,
    const float* __restrict__ bq, const float* __restrict__ bk,
    const float* __restrict__ bv) {
  alignas(16) __shared__ short As[128 * 32];
  alignas(16) __shared__ short Bs[128 * 32];
  GEMM_PRE();
  f32x4 acc[4][4];
#pragma unroll
  for (int m = 0; m < 4; m++)
#pragma unroll
    for (int n = 0; n < 4; n++) acc[m][n] = zero4;
  for (int k0 = 0; k0 < D_; k0 += 32) {
    stage_tile(A, D_, m0, k0, (char*)As, tid);
    stage_tile(Bt, D_, n0, k0, (char*)Bs, tid);
    __syncthreads();
    gemm_step((const char*)As, (const char*)Bs, wr, wc, g, lr, acc);
    __syncthreads();
  }
#pragma unroll
  for (int m = 0; m < 4; m++)
#pragma unroll
    for (int n = 0; n < 4; n++)
#pragma unroll
      for (int r = 0; r < 4; r++) {
        int row = m0 + wr + m * 16 + (g << 2) + r;
        int col = n0 + wc + n * 16 + lr;
        float bias = (col < D_) ? bq[col] : ((col < 2 * D_) ? bk[col - D_] : bv[col - 2 * D_]);
        C[(size_t)row * D3_ + col] = f2bf(acc[m][n][r] + bias);
      }
}

// ---------- K7: RoPE + head relayout (q,k row-major per head; v transposed) ----------
__global__ __launch_bounds__(256) void k_rope(const unsigned short* __restrict__ qkv,
    const float* __restrict__ cosb, const float* __restrict__ sinb,
    unsigned short* __restrict__ qh, unsigned short* __restrict__ kh,
    unsigned short* __restrict__ vT) {
  int s0 = blockIdx.x * 64;
  int h = blockIdx.y;
  int t = threadIdx.x;
#pragma unroll
  for (int i = 0; i < 16; i++) {
    int flat = t + i * 256;
    int r = flat >> 6, dp = flat & 63;
    int s = s0 + r;
    float c = cosb[s * 64 + dp], sn = sinb[s * 64 + dp];
    const unsigned short* qrow = qkv + (size_t)s * D3_ + h * HD_;
    float q1 = bf2f(qrow[dp]), q2 = bf2f(qrow[dp + 64]);
    unsigned short* qdst = qh + ((size_t)h * S_ + s) * HD_;
    qdst[dp] = f2bf(q1 * c - q2 * sn);
    qdst[dp + 64] = f2bf(q2 * c + q1 * sn);
    const unsigned short* krow = qrow + D_;
    float k1 = bf2f(krow[dp]), k2 = bf2f(krow[dp + 64]);
    unsigned short* kdst = kh + ((size_t)h * S_ + s) * HD_;
    kdst[dp] = f2bf(k1 * c - k2 * sn);
    kdst[dp + 64] = f2bf(k2 * c + k1 * sn);
  }
  __shared__ unsigned short vt[128][66];
#pragma unroll
  for (int i = 0; i < 32; i++) {
    int flat = t + i * 256;
    int r = flat >> 7, d = flat & 127;
    vt[d][r] = qkv[(size_t)(s0 + r) * D3_ + 2 * D_ + h * HD_ + d];
  }
  __syncthreads();
#pragma unroll
  for (int i = 0; i < 32; i++) {
    int flat = t + i * 256;
    int d = flat >> 6, sc = flat & 63;
    vT[((size_t)h * HD_ + d) * S_ + s0 + sc] = vt[d][sc];
  }
}

// ---------- K8: flash attention over packed sequence (causal on S) ----------
__global__ __launch_bounds__(256) void k_attn(const unsigned short* __restrict__ qh,
                                              const unsigned short* __restrict__ kh,
                                              const unsigned short* __restrict__ vT,
                                              unsigned short* __restrict__ ao) {
  alignas(16) __shared__ short Ks[64 * 128];   // [kv][d]
  alignas(16) __shared__ short Vs[128 * 64];   // [d][kv]
  alignas(16) __shared__ short Ps[4][32 * 64]; // per-wave P
  int h = blockIdx.y;
  int q0 = blockIdx.x * 128;
  int tid = threadIdx.x, w = tid >> 6, lane = tid & 63, g = lane >> 4, lr = lane & 15;
  size_t hbase = (size_t)h * S_ * HD_;
  int qw = q0 + w * 32;
  s16x8 qf[2][4];
#pragma unroll
  for (int mf = 0; mf < 2; mf++)
#pragma unroll
    for (int ks = 0; ks < 4; ks++)
      qf[mf][ks] = *(const s16x8*)&qh[hbase + (size_t)(qw + mf * 16 + lr) * HD_ + ks * 32 + g * 8];
  f32x4 o[2][8];
  f32x4 zero4 = {0.f, 0.f, 0.f, 0.f};
#pragma unroll
  for (int mf = 0; mf < 2; mf++)
#pragma unroll
    for (int nf = 0; nf < 8; nf++) o[mf][nf] = zero4;
  float m_i[2][4], l_i[2][4];
#pragma unroll
  for (int mf = 0; mf < 2; mf++)
#pragma unroll
    for (int r = 0; r < 4; r++) { m_i[mf][r] = -1e30f; l_i[mf][r] = 0.f; }
  const float sc = 0.08838834764831843f;  // 1/sqrt(128)
  int ktiles = (q0 + 128) >> 6;
  for (int kt = 0; kt < ktiles; kt++) {
#pragma unroll
    for (int p = 0; p < 4; p++) {
      int ldsoff = p * 4096 + w * 1024;
      int boff = ldsoff + lane * 16;
      int krow = boff >> 8, kcolb = boff & 255;
      gl_lds16(kh + hbase + (size_t)(kt * 64 + krow) * HD_ + (kcolb >> 1), (char*)Ks + ldsoff);
      int vrow = boff >> 7, vcol = (boff & 127) >> 1;
      gl_lds16(vT + hbase + (size_t)vrow * S_ + kt * 64 + vcol, (char*)Vs + ldsoff);
    }
    __syncthreads();
    bool active = (kt * 64) <= (qw + 31);
    if (active) {
      f32x4 sacc[2][4];
#pragma unroll
      for (int mf = 0; mf < 2; mf++)
#pragma unroll
        for (int nf = 0; nf < 4; nf++) sacc[mf][nf] = zero4;
#pragma unroll
      for (int ks = 0; ks < 4; ks++) {
        s16x8 kf[4];
#pragma unroll
        for (int nf = 0; nf < 4; nf++)
          kf[nf] = *(const s16x8*)((const char*)Ks + ((nf * 16 + lr) << 8) + (ks << 6) + (g << 4));
#pragma unroll
        for (int mf = 0; mf < 2; mf++)
#pragma unroll
          for (int nf = 0; nf < 4; nf++)
            sacc[mf][nf] = mfma_bf16(qf[mf][ks], kf[nf], sacc[mf][nf]);
      }
#pragma unroll
      for (int mf = 0; mf < 2; mf++)
#pragma unroll
        for (int r = 0; r < 4; r++) {
          int qrow = qw + mf * 16 + (g << 2) + r;
          float pv[4];
          float mx = -1e30f;
#pragma unroll
          for (int nf = 0; nf < 4; nf++) {
            int kc = kt * 64 + nf * 16 + lr;
            float vv = sacc[mf][nf][r] * sc;
            vv = (kc <= qrow) ? vv : -1e30f;
            pv[nf] = vv;
            mx = fmaxf(mx, vv);
          }
#pragma unroll
          for (int d = 1; d < 16; d <<= 1) mx = fmaxf(mx, __shfl_xor(mx, d));
          float mold = m_i[mf][r], mnew = fmaxf(mold, mx);
          float corr = __expf(mold - mnew);
          float ssum = 0.f;
#pragma unroll
          for (int nf = 0; nf < 4; nf++) {
            float pe = __expf(pv[nf] - mnew);
            Ps[w][(mf * 16 + (g << 2) + r) * 64 + nf * 16 + lr] = (short)f2bf(pe);
            ssum += pe;
          }
#pragma unroll
          for (int d = 1; d < 16; d <<= 1) ssum += __shfl_xor(ssum, d);
          l_i[mf][r] = l_i[mf][r] * corr + ssum;
          m_i[mf][r] = mnew;
#pragma unroll
          for (int nf = 0; nf < 8; nf++) o[mf][nf][r] *= corr;
        }
    }
    __syncthreads();
    if (active) {
#pragma unroll
      for (int ks = 0; ks < 2; ks++) {
        s16x8 pa[2];
#pragma unroll
        for (int mf = 0; mf < 2; mf++)
          pa[mf] = *(const s16x8*)((const char*)&Ps[w][0] + ((mf * 16 + lr) << 7) + (ks << 6) + (g << 4));
#pragma unroll
        for (int nf = 0; nf < 8; nf++) {
          s16x8 vb = *(const s16x8*)((const char*)Vs + ((nf * 16 + lr) << 7) + (ks << 6) + (g << 4));
#pragma unroll
          for (int mf = 0; mf < 2; mf++) o[mf][nf] = mfma_bf16(pa[mf], vb, o[mf][nf]);
        }
      }
    }
    __syncthreads();
  }
#pragma unroll
  for (int mf = 0; mf < 2; mf++)
#pragma unroll
    for (int nf = 0; nf < 8; nf++)
#pragma unroll
      for (int r = 0; r < 4; r++) {
        int row = qw + mf * 16 + (g << 2) + r;
        int col = h * HD_ + nf * 16 + lr;
        ao[(size_t)row * D_ + col] = f2bf(o[mf][nf][r] / l_i[mf][r]);
      }
}

// ---------- K9: wo GEMM + residual ----------
__global__ __launch_bounds__(256) void k_gemm_wo(const unsigned short* __restrict__ A,
    const unsigned short* __restrict__ Bt, const float* __restrict__ xres,
    float* __restrict__ x1) {
  alignas(16) __shared__ short As[128 * 32];
  alignas(16) __shared__ short Bs[128 * 32];
  GEMM_PRE();
  f32x4 acc[4][4];
#pragma unroll
  for (int m = 0; m < 4; m++)
#pragma unroll
    for (int n = 0; n < 4; n++) acc[m][n] = zero4;
  for (int k0 = 0; k0 < D_; k0 += 32) {
    stage_tile(A, D_, m0, k0, (char*)As, tid);
    stage_tile(Bt, D_, n0, k0, (char*)Bs, tid);
    __syncthreads();
    gemm_step((const char*)As, (const char*)Bs, wr, wc, g, lr, acc);
    __syncthreads();
  }
#pragma unroll
  for (int m = 0; m < 4; m++)
#pragma unroll
    for (int n = 0; n < 4; n++)
#pragma unroll
      for (int r = 0; r < 4; r++) {
        int row = m0 + wr + m * 16 + (g << 2) + r;
        int col = n0 + wc + n * 16 + lr;
        x1[(size_t)row * D_ + col] = acc[m][n][r] + xres[(size_t)row * D_ + col];
      }
}

// ---------- K10: RMS2 ----------
__global__ __launch_bounds__(256) void k_rms2(const float* __restrict__ x1,
                                              const float* __restrict__ ln2w,
                                              unsigned short* __restrict__ xn2) {
  int s = blockIdx.x, t = threadIdx.x;
  const float* src = x1 + (size_t)s * D_;
  float v[8];
  float ss = 0.f;
#pragma unroll
  for (int i = 0; i < 8; i++) { v[i] = src[t + i * 256]; ss += v[i] * v[i]; }
  __shared__ float red[4];
#pragma unroll
  for (int d = 32; d; d >>= 1) ss += __shfl_xor(ss, d);
  if ((t & 63) == 0) red[t >> 6] = ss;
  __syncthreads();
  ss = red[0] + red[1] + red[2] + red[3];
  float scale = rsqrtf(ss / (float)D_ + 1e-6f);
  unsigned short* dst = xn2 + (size_t)s * D_;
#pragma unroll
  for (int i = 0; i < 8; i++) {
    int c = t + i * 256;
    dst[c] = f2bf(v[i] * scale * ln2w[c]);
  }
}

// ---------- K11: fused gate/up GEMM + silu*mul epilogue ----------
__global__ __launch_bounds__(256) void k_gemm_gateup(const unsigned short* __restrict__ A,
    const unsigned short* __restrict__ Bg, const unsigned short* __restrict__ Bu,
    unsigned short* __restrict__ act) {
  alignas(16) __shared__ short As[128 * 32];
  alignas(16) __shared__ short Bs0[128 * 32];
  alignas(16) __shared__ short Bs1[128 * 32];
  GEMM_PRE();
  f32x4 ag[4][4], au[4][4];
#pragma unroll
  for (int m = 0; m < 4; m++)
#pragma unroll
    for (int n = 0; n < 4; n++) { ag[m][n] = zero4; au[m][n] = zero4; }
  for (int k0 = 0; k0 < D_; k0 += 32) {
    stage_tile(A, D_, m0, k0, (char*)As, tid);
    stage_tile(Bg, D_, n0, k0, (char*)Bs0, tid);
    stage_tile(Bu, D_, n0, k0, (char*)Bs1, tid);
    __syncthreads();
    gemm_step((const char*)As, (const char*)Bs0, wr, wc, g, lr, ag);
    gemm_step((const char*)As, (const char*)Bs1, wr, wc, g, lr, au);
    __syncthreads();
  }
#pragma unroll
  for (int m = 0; m < 4; m++)
#pragma unroll
    for (int n = 0; n < 4; n++)
#pragma unroll
      for (int r = 0; r < 4; r++) {
        int row = m0 + wr + m * 16 + (g << 2) + r;
        int col = n0 + wc + n * 16 + lr;
        float gv = ag[m][n][r], uv = au[m][n][r];
        float si = gv / (1.f + __expf(-gv));
        act[(size_t)row * I_ + col] = f2bf(si * uv);
      }
}

// ---------- K12: down GEMM + residual + sigmoid blend + scatter ----------
__global__ __launch_bounds__(256) void k_gemm_down(const unsigned short* __restrict__ A,
    const unsigned short* __restrict__ Bt, const float* __restrict__ x1,
    const float* __restrict__ x, const float* __restrict__ gate,
    const int* __restrict__ pos, float* __restrict__ out) {
  alignas(16) __shared__ short As[128 * 32];
  alignas(16) __shared__ short Bs[128 * 32];
  GEMM_PRE();
  f32x4 acc[4][4];
#pragma unroll
  for (int m = 0; m < 4; m++)
#pragma unroll
    for (int n = 0; n < 4; n++) acc[m][n] = zero4;
  for (int k0 = 0; k0 < I_; k0 += 32) {
    stage_tile(A, I_, m0, k0, (char*)As, tid);
    stage_tile(Bt, I_, n0, k0, (char*)Bs, tid);
    __syncthreads();
    gemm_step((const char*)As, (const char*)Bs, wr, wc, g, lr, acc);
    __syncthreads();
  }
#pragma unroll
  for (int m = 0; m < 4; m++)
#pragma unroll
    for (int n = 0; n < 4; n++)
#pragma unroll
      for (int r = 0; r < 4; r++) {
        int srow = m0 + wr + m * 16 + (g << 2) + r;
        int col = n0 + wc + n * 16 + lr;
        float proc = acc[m][n][r] + x1[(size_t)srow * D_ + col];
        float gt = gate[srow];
        float xv = x[(size_t)srow * D_ + col];
        int bb = srow >> 9;
        int p = pos[srow];
        out[((size_t)bb * T_ + p) * D_ + col] = gt * proc + (1.f - gt) * xv;
      }
}

extern "C" void kernel_launch(void* const* d_in, const int* in_sizes, int n_in,
                              void* d_out, int out_size, void* d_ws, size_t ws_size,
                              hipStream_t stream) {
  (void)in_sizes; (void)n_in; (void)out_size; (void)ws_size;
  const float* hidden = (const float*)d_in[0];
  const float* router_w = (const float*)d_in[1];
  const float* router_b = (const float*)d_in[2];
  const float* ln1w = (const float*)d_in[3];
  const float* ln2w = (const float*)d_in[4];
  const float* wq = (const float*)d_in[5];
  const float* bq = (const float*)d_in[6];
  const float* wk = (const float*)d_in[7];
  const float* bk = (const float*)d_in[8];
  const float* wv = (const float*)d_in[9];
  const float* bv = (const float*)d_in[10];
  const float* wo = (const float*)d_in[11];
  const float* wg = (const float*)d_in[12];
  const float* wu = (const float*)d_in[13];
  const float* wd = (const float*)d_in[14];
  float* out = (float*)d_out;

  char* ws = (char*)d_ws;
  size_t off = 0;
  auto alloc = [&](size_t bytes) {
    char* p = ws + off;
    off += (bytes + 255) & ~(size_t)255;
    return p;
  };
  unsigned short* wqkvT = (unsigned short*)alloc(3ull * D_ * D_ * 2);
  unsigned short* woT = (unsigned short*)alloc((size_t)D_ * D_ * 2);
  unsigned short* wgT = (unsigned short*)alloc((size_t)I_ * D_ * 2);
  unsigned short* wuT = (unsigned short*)alloc((size_t)I_ * D_ * 2);
  unsigned short* wdT = (unsigned short*)alloc((size_t)D_ * I_ * 2);
  float* scores = (float*)alloc((size_t)B_ * T_ * 4);
  int* pos = (int*)alloc((size_t)S_ * 4);
  float* gate = (float*)alloc((size_t)S_ * 4);
  float* x = (float*)alloc((size_t)S_ * D_ * 4);
  float* x1 = (float*)alloc((size_t)S_ * D_ * 4);
  unsigned short* xn = (unsigned short*)alloc((size_t)S_ * D_ * 2);  // reused as x1n
  float* cosb = (float*)alloc((size_t)S_ * 64 * 4);
  float* sinb = (float*)alloc((size_t)S_ * 64 * 4);
  unsigned short* qkv = (unsigned short*)alloc((size_t)S_ * D3_ * 2);  // reused as act
  unsigned short* qh = (unsigned short*)alloc((size_t)H_ * S_ * HD_ * 2);
  unsigned short* kh = (unsigned short*)alloc((size_t)H_ * S_ * HD_ * 2);
  unsigned short* vT = (unsigned short*)alloc((size_t)H_ * S_ * HD_ * 2);
  unsigned short* ao = (unsigned short*)alloc((size_t)S_ * D_ * 2);

  k_copy<<<4096, 256, 0, stream>>>((const float4*)hidden, (float4*)out, B_ * T_ * D_ / 4);

  k_transpose<<<dim3(D_ / 32, D_ / 32), 256, 0, stream>>>(wq, wqkvT, D_, D_);
  k_transpose<<<dim3(D_ / 32, D_ / 32), 256, 0, stream>>>(wk, wqkvT + (size_t)D_ * D_, D_, D_);
  k_transpose<<<dim3(D_ / 32, D_ / 32), 256, 0, stream>>>(wv, wqkvT + 2ull * D_ * D_, D_, D_);
  k_transpose<<<dim3(D_ / 32, D_ / 32), 256, 0, stream>>>(wo, woT, D_, D_);
  k_transpose<<<dim3(I_ / 32, D_ / 32), 256, 0, stream>>>(wg, wgT, D_, I_);
  k_transpose<<<dim3(I_ / 32, D_ / 32), 256, 0, stream>>>(wu, wuT, D_, I_);
  k_transpose<<<dim3(D_ / 32, I_ / 32), 256, 0, stream>>>(wd, wdT, I_, D_);

  k_scores<<<B_ * T_ / 4, 256, 0, stream>>>(hidden, router_w, router_b, scores);
  k_topk<<<B_, 1024, 0, stream>>>(scores, pos);
  k_gather<<<S_, 256, 0, stream>>>(hidden, pos, scores, ln1w, x, xn, gate, cosb, sinb);

  k_gemm_qkv<<<dim3(S_ / 128, D3_ / 128), 256, 0, stream>>>(xn, wqkvT, qkv, bq, bk, bv);
  k_rope<<<dim3(S_ / 64, H_), 256, 0, stream>>>(qkv, cosb, sinb, qh, kh, vT);
  k_attn<<<dim3(S_ / 128, H_), 256, 0, stream>>>(qh, kh, vT, ao);
  k_gemm_wo<<<dim3(S_ / 128, D_ / 128), 256, 0, stream>>>(ao, woT, x, x1);
  k_rms2<<<S_, 256, 0, stream>>>(x1, ln2w, xn);
  k_gemm_gateup<<<dim3(S_ / 128, I_ / 128), 256, 0, stream>>>(xn, wgT, wuT, qkv);
  k_gemm_down<<<dim3(S_ / 128, D_ / 128), 256, 0, stream>>>(qkv, wdT, x1, x, gate, pos, out);
}

// Round 2
// 761.493 us; speedup vs baseline: 1.0690x; 1.0690x over previous
//
#include <hip/hip_runtime.h>
#include <stdint.h>

#define B_ 4
#define T_ 2048
#define D_ 2048
#define H_ 16
#define HD_ 128
#define I_ 5632
#define K_ 512
#define S_ 2048
#define D3_ (3 * D_)

typedef float f32x4 __attribute__((ext_vector_type(4)));
typedef short s16x8 __attribute__((ext_vector_type(8)));
typedef __bf16 bf16x8 __attribute__((ext_vector_type(8)));

// ---------- mfma wrapper robust to builtin operand type (short8 vs bf16x8) ----------
template <typename V>
__device__ __forceinline__ auto mfma_try(V a, V b, f32x4 c, int)
    -> decltype(__builtin_amdgcn_mfma_f32_16x16x32_bf16(a, b, c, 0, 0, 0)) {
  return __builtin_amdgcn_mfma_f32_16x16x32_bf16(a, b, c, 0, 0, 0);
}
template <typename V>
__device__ __forceinline__ f32x4 mfma_try(V a, V b, f32x4 c, long) {
  return __builtin_amdgcn_mfma_f32_16x16x32_bf16(
      __builtin_bit_cast(bf16x8, a), __builtin_bit_cast(bf16x8, b), c, 0, 0, 0);
}
__device__ __forceinline__ f32x4 mfma_bf16(s16x8 a, s16x8 b, f32x4 c) {
  return mfma_try(a, b, c, 0);
}

__device__ __forceinline__ void gl_lds16(const void* g, void* l) {
  __builtin_amdgcn_global_load_lds((const __attribute__((address_space(1))) void*)g,
                                   (__attribute__((address_space(3))) void*)l, 16, 0, 0);
}

__device__ __forceinline__ unsigned short f2bf(float f) {
  unsigned u = __float_as_uint(f);
  u += 0x7FFFu + ((u >> 16) & 1);
  return (unsigned short)(u >> 16);
}
__device__ __forceinline__ float bf2f(unsigned short s) {
  return __uint_as_float(((unsigned)s) << 16);
}

// ---------- K1: copy hidden -> out, fused with router scores ----------
__global__ __launch_bounds__(256) void k_copy_scores(const float4* __restrict__ hid,
                                                     float4* __restrict__ dst,
                                                     const float4* __restrict__ rw,
                                                     const float* __restrict__ rb,
                                                     float* __restrict__ scores) {
  int row = blockIdx.x, t = threadIdx.x;
  const float4* hr = hid + (size_t)row * (D_ / 4);
  float4* dr = dst + (size_t)row * (D_ / 4);
  float acc = 0.f;
#pragma unroll
  for (int i = 0; i < 2; i++) {
    float4 v = hr[t + i * 256];
    dr[t + i * 256] = v;
    float4 w = rw[t + i * 256];
    acc += v.x * w.x + v.y * w.y + v.z * w.z + v.w * w.w;
  }
#pragma unroll
  for (int d = 32; d; d >>= 1) acc += __shfl_xor(acc, d);
  __shared__ float red[4];
  if ((t & 63) == 0) red[t >> 6] = acc;
  __syncthreads();
  if (t == 0) scores[row] = red[0] + red[1] + red[2] + red[3] + rb[0];
}

// ---------- K3: exact top-k (bitonic, matches jax.lax.top_k tie-break) ----------
__global__ __launch_bounds__(1024) void k_topk(const float* __restrict__ scores,
                                               int* __restrict__ pos) {
  __shared__ unsigned long long keys[T_];
  __shared__ int sidx[K_];
  int b = blockIdx.x, t = threadIdx.x;
  for (int i = t; i < T_; i += 1024) {
    unsigned u = __float_as_uint(scores[b * T_ + i]);
    u = (u & 0x80000000u) ? ~u : (u | 0x80000000u);
    keys[i] = ((unsigned long long)u << 32) | (unsigned)(~(unsigned)i);
  }
  __syncthreads();
  for (int k = 2; k <= T_; k <<= 1)
    for (int j = k >> 1; j > 0; j >>= 1) {
      for (int i = t; i < T_; i += 1024) {
        int l = i ^ j;
        if (l > i) {
          unsigned long long a = keys[i], c = keys[l];
          bool desc = ((i & k) == 0);
          if (desc ? (a < c) : (a > c)) { keys[i] = c; keys[l] = a; }
        }
      }
      __syncthreads();
    }
  if (t < K_) sidx[t] = (int)(~(unsigned)(keys[t] & 0xFFFFFFFFull));
  __syncthreads();
  for (int k = 2; k <= K_; k <<= 1)
    for (int j = k >> 1; j > 0; j >>= 1) {
      if (t < K_) {
        int i = t, l = i ^ j;
        if (l > i && l < K_) {
          int a = sidx[i], c = sidx[l];
          bool asc = ((i & k) == 0);
          if (asc ? (a > c) : (a < c)) { sidx[i] = c; sidx[l] = a; }
        }
      }
      __syncthreads();
    }
  if (t < K_) pos[b * K_ + t] = sidx[t];
}

// ---------- K4: gather + RMS1 + gate + rope tables ----------
__global__ __launch_bounds__(256) void k_gather(const float* __restrict__ hidden,
    const int* __restrict__ pos, const float* __restrict__ scores,
    const float* __restrict__ ln1w, float* __restrict__ x,
    unsigned short* __restrict__ xn, float* __restrict__ gate,
    float* __restrict__ cosb, float* __restrict__ sinb) {
  int s = blockIdx.x, t = threadIdx.x;
  int b = s >> 9, p = pos[s];
  const float* src = hidden + ((size_t)b * T_ + p) * D_;
  float v[8];
  float ss = 0.f;
#pragma unroll
  for (int i = 0; i < 8; i++) { v[i] = src[t + i * 256]; ss += v[i] * v[i]; }
  __shared__ float red[4];
#pragma unroll
  for (int d = 32; d; d >>= 1) ss += __shfl_xor(ss, d);
  if ((t & 63) == 0) red[t >> 6] = ss;
  __syncthreads();
  ss = red[0] + red[1] + red[2] + red[3];
  float scale = rsqrtf(ss / (float)D_ + 1e-6f);
  float* xd = x + (size_t)s * D_;
  unsigned short* xnd = xn + (size_t)s * D_;
#pragma unroll
  for (int i = 0; i < 8; i++) {
    int c = t + i * 256;
    xd[c] = v[i];
    xnd[c] = f2bf(v[i] * scale * ln1w[c]);
  }
  if (t == 0) gate[s] = 1.f / (1.f + expf(-scores[b * T_ + p]));
  if (t < 64) {
    float invf = powf(10000.0f, -(float)t / 64.0f);
    float f = (float)p * invf;
    cosb[s * 64 + t] = cosf(f);
    sinb[s * 64 + t] = sinf(f);
  }
}

// ---------- K5: transpose + f32->bf16 (weights to Bt layout) ----------
__global__ __launch_bounds__(256) void k_transpose(const float* __restrict__ src,
                                                   unsigned short* __restrict__ dst,
                                                   int R, int C) {
  __shared__ float tile[32][33];
  int tx = threadIdx.x & 31, ty = threadIdx.x >> 5;
  int c0 = blockIdx.x * 32, r0 = blockIdx.y * 32;
#pragma unroll
  for (int i = 0; i < 4; i++) {
    int r = ty + i * 8;
    tile[r][tx] = src[(size_t)(r0 + r) * C + c0 + tx];
  }
  __syncthreads();
#pragma unroll
  for (int i = 0; i < 4; i++) {
    int r = ty + i * 8;
    dst[(size_t)(c0 + r) * R + r0 + tx] = f2bf(tile[tx][r]);
  }
}

// ---------- GEMM building blocks (128x128 tile, BK=32, dbuf 2-phase) ----------
__device__ __forceinline__ void stage_tile(const unsigned short* __restrict__ gbase,
                                           int ldK, int row0, int k0, char* lds, int tid) {
  int w = tid >> 6, lane = tid & 63;
#pragma unroll
  for (int p = 0; p < 2; p++) {
    int ldsoff = p * 4096 + w * 1024;
    int boff = ldsoff + lane * 16;
    int row = boff >> 6;
    int ke = (boff & 63) >> 1;
    gl_lds16(gbase + (size_t)(row0 + row) * ldK + k0 + ke, lds + ldsoff);
  }
}

__device__ __forceinline__ void gemm_step(const char* As, const char* Bs, int wr, int wc,
                                          int g, int lr, f32x4 acc[4][4]) {
  s16x8 af[4], bf4[4];
#pragma unroll
  for (int i = 0; i < 4; i++)
    af[i] = *(const s16x8*)(As + ((wr + i * 16 + lr) << 6) + (g << 4));
#pragma unroll
  for (int i = 0; i < 4; i++)
    bf4[i] = *(const s16x8*)(Bs + ((wc + i * 16 + lr) << 6) + (g << 4));
#pragma unroll
  for (int m = 0; m < 4; m++)
#pragma unroll
    for (int n = 0; n < 4; n++) acc[m][n] = mfma_bf16(af[m], bf4[n], acc[m][n]);
}

#define GEMM_PRE()                                                     \
  int tid = threadIdx.x;                                               \
  int w = tid >> 6, lane = tid & 63, g = lane >> 4, lr = lane & 15;    \
  int wr = (w >> 1) * 64, wc = (w & 1) * 64;                           \
  int m0 = blockIdx.x * 128, n0 = blockIdx.y * 128;                    \
  f32x4 zero4 = {0.f, 0.f, 0.f, 0.f};                                  \
  (void)lane;

// ---------- K6: fused QKV GEMM (bias epilogue) ----------
__global__ __launch_bounds__(256) void k_gemm_qkv(const unsigned short* __restrict__ A,
    const unsigned short* __restrict__ Bt, unsigned short* __restrict__ C,
    const float* __restrict__ bq, const float* __restrict__ bk,
    const float* __restrict__ bv) {
  alignas(16) __shared__ short As[2][128 * 32];
  alignas(16) __shared__ short Bs[2][128 * 32];
  GEMM_PRE();
  f32x4 acc[4][4];
#pragma unroll
  for (int m = 0; m < 4; m++)
#pragma unroll
    for (int n = 0; n < 4; n++) acc[m][n] = zero4;
  stage_tile(A, D_, m0, 0, (char*)As[0], tid);
  stage_tile(Bt, D_, n0, 0, (char*)Bs[0], tid);
  __syncthreads();
  int cur = 0;
  for (int k0 = 0; k0 < D_; k0 += 32) {
    if (k0 + 32 < D_) {
      stage_tile(A, D_, m0, k0 + 32, (char*)As[cur ^ 1], tid);
      stage_tile(Bt, D_, n0, k0 + 32, (char*)Bs[cur ^ 1], tid);
    }
    gemm_step((const char*)As[cur], (const char*)Bs[cur], wr, wc, g, lr, acc);
    __syncthreads();
    cur ^= 1;
  }
#pragma unroll
  for (int m = 0; m < 4; m++)
#pragma unroll
    for (int n = 0; n < 4; n++)
#pragma unroll
      for (int r = 0; r < 4; r++) {
        int row = m0 + wr + m * 16 + (g << 2) + r;
        int col = n0 + wc + n * 16 + lr;
        float bias = (col < D_) ? bq[col] : ((col < 2 * D_) ? bk[col - D_] : bv[col - 2 * D_]);
        C[(size_t)row * D3_ + col] = f2bf(acc[m][n][r] + bias);
      }
}

// ---------- K7: RoPE + head relayout (q,k row-major per head; v transposed) ----------
__global__ __launch_bounds__(256) void k_rope(const unsigned short* __restrict__ qkv,
    const float* __restrict__ cosb, const float* __restrict__ sinb,
    unsigned short* __restrict__ qh, unsigned short* __restrict__ kh,
    unsigned short* __restrict__ vT) {
  int s0 = blockIdx.x * 64;
  int h = blockIdx.y;
  int t = threadIdx.x;
#pragma unroll
  for (int i = 0; i < 16; i++) {
    int flat = t + i * 256;
    int r = flat >> 6, dp = flat & 63;
    int s = s0 + r;
    float c = cosb[s * 64 + dp], sn = sinb[s * 64 + dp];
    const unsigned short* qrow = qkv + (size_t)s * D3_ + h * HD_;
    float q1 = bf2f(qrow[dp]), q2 = bf2f(qrow[dp + 64]);
    unsigned short* qdst = qh + ((size_t)h * S_ + s) * HD_;
    qdst[dp] = f2bf(q1 * c - q2 * sn);
    qdst[dp + 64] = f2bf(q2 * c + q1 * sn);
    const unsigned short* krow = qrow + D_;
    float k1 = bf2f(krow[dp]), k2 = bf2f(krow[dp + 64]);
    unsigned short* kdst = kh + ((size_t)h * S_ + s) * HD_;
    kdst[dp] = f2bf(k1 * c - k2 * sn);
    kdst[dp + 64] = f2bf(k2 * c + k1 * sn);
  }
  __shared__ unsigned short vt[128][66];
#pragma unroll
  for (int i = 0; i < 32; i++) {
    int flat = t + i * 256;
    int r = flat >> 7, d = flat & 127;
    vt[d][r] = qkv[(size_t)(s0 + r) * D3_ + 2 * D_ + h * HD_ + d];
  }
  __syncthreads();
#pragma unroll
  for (int i = 0; i < 32; i++) {
    int flat = t + i * 256;
    int d = flat >> 6, sc = flat & 63;
    vT[((size_t)h * HD_ + d) * S_ + s0 + sc] = vt[d][sc];
  }
}

// ---------- K8: flash attention over packed sequence (causal on S) ----------
__global__ __launch_bounds__(256) void k_attn(const unsigned short* __restrict__ qh,
                                              const unsigned short* __restrict__ kh,
                                              const unsigned short* __restrict__ vT,
                                              unsigned short* __restrict__ ao) {
  alignas(16) __shared__ short Ks[64 * 128];   // [kv][d]
  alignas(16) __shared__ short Vs[128 * 64];   // [d][kv]
  alignas(16) __shared__ short Ps[4][32 * 64]; // per-wave P
  int h = blockIdx.y;
  int q0 = blockIdx.x * 128;
  int tid = threadIdx.x, w = tid >> 6, lane = tid & 63, g = lane >> 4, lr = lane & 15;
  size_t hbase = (size_t)h * S_ * HD_;
  int qw = q0 + w * 32;
  s16x8 qf[2][4];
#pragma unroll
  for (int mf = 0; mf < 2; mf++)
#pragma unroll
    for (int ks = 0; ks < 4; ks++)
      qf[mf][ks] = *(const s16x8*)&qh[hbase + (size_t)(qw + mf * 16 + lr) * HD_ + ks * 32 + g * 8];
  f32x4 o[2][8];
  f32x4 zero4 = {0.f, 0.f, 0.f, 0.f};
#pragma unroll
  for (int mf = 0; mf < 2; mf++)
#pragma unroll
    for (int nf = 0; nf < 8; nf++) o[mf][nf] = zero4;
  float m_i[2][4], l_i[2][4];
#pragma unroll
  for (int mf = 0; mf < 2; mf++)
#pragma unroll
    for (int r = 0; r < 4; r++) { m_i[mf][r] = -1e30f; l_i[mf][r] = 0.f; }
  const float sc = 0.08838834764831843f;  // 1/sqrt(128)
  int ktiles = (q0 + 128) >> 6;
  for (int kt = 0; kt < ktiles; kt++) {
#pragma unroll
    for (int p = 0; p < 4; p++) {
      int ldsoff = p * 4096 + w * 1024;
      int boff = ldsoff + lane * 16;
      int krow = boff >> 8, kcolb = boff & 255;
      gl_lds16(kh + hbase + (size_t)(kt * 64 + krow) * HD_ + (kcolb >> 1), (char*)Ks + ldsoff);
      int vrow = boff >> 7, vcol = (boff & 127) >> 1;
      gl_lds16(vT + hbase + (size_t)vrow * S_ + kt * 64 + vcol, (char*)Vs + ldsoff);
    }
    __syncthreads();
    bool active = (kt * 64) <= (qw + 31);
    if (active) {
      f32x4 sacc[2][4];
#pragma unroll
      for (int mf = 0; mf < 2; mf++)
#pragma unroll
        for (int nf = 0; nf < 4; nf++) sacc[mf][nf] = zero4;
#pragma unroll
      for (int ks = 0; ks < 4; ks++) {
        s16x8 kf[4];
#pragma unroll
        for (int nf = 0; nf < 4; nf++)
          kf[nf] = *(const s16x8*)((const char*)Ks + ((nf * 16 + lr) << 8) + (ks << 6) + (g << 4));
#pragma unroll
        for (int mf = 0; mf < 2; mf++)
#pragma unroll
          for (int nf = 0; nf < 4; nf++)
            sacc[mf][nf] = mfma_bf16(qf[mf][ks], kf[nf], sacc[mf][nf]);
      }
#pragma unroll
      for (int mf = 0; mf < 2; mf++)
#pragma unroll
        for (int r = 0; r < 4; r++) {
          int qrow = qw + mf * 16 + (g << 2) + r;
          float pv[4];
          float mx = -1e30f;
#pragma unroll
          for (int nf = 0; nf < 4; nf++) {
            int kc = kt * 64 + nf * 16 + lr;
            float vv = sacc[mf][nf][r] * sc;
            vv = (kc <= qrow) ? vv : -1e30f;
            pv[nf] = vv;
            mx = fmaxf(mx, vv);
          }
#pragma unroll
          for (int d = 1; d < 16; d <<= 1) mx = fmaxf(mx, __shfl_xor(mx, d));
          float mold = m_i[mf][r], mnew = fmaxf(mold, mx);
          float corr = __expf(mold - mnew);
          float ssum = 0.f;
#pragma unroll
          for (int nf = 0; nf < 4; nf++) {
            float pe = __expf(pv[nf] - mnew);
            Ps[w][(mf * 16 + (g << 2) + r) * 64 + nf * 16 + lr] = (short)f2bf(pe);
            ssum += pe;
          }
#pragma unroll
          for (int d = 1; d < 16; d <<= 1) ssum += __shfl_xor(ssum, d);
          l_i[mf][r] = l_i[mf][r] * corr + ssum;
          m_i[mf][r] = mnew;
#pragma unroll
          for (int nf = 0; nf < 8; nf++) o[mf][nf][r] *= corr;
        }
      // Ps is per-wave: no __syncthreads needed between write and PV read.
#pragma unroll
      for (int ks = 0; ks < 2; ks++) {
        s16x8 pa[2];
#pragma unroll
        for (int mf = 0; mf < 2; mf++)
          pa[mf] = *(const s16x8*)((const char*)&Ps[w][0] + ((mf * 16 + lr) << 7) + (ks << 6) + (g << 4));
#pragma unroll
        for (int nf = 0; nf < 8; nf++) {
          s16x8 vb = *(const s16x8*)((const char*)Vs + ((nf * 16 + lr) << 7) + (ks << 6) + (g << 4));
#pragma unroll
          for (int mf = 0; mf < 2; mf++) o[mf][nf] = mfma_bf16(pa[mf], vb, o[mf][nf]);
        }
      }
    }
    __syncthreads();
  }
#pragma unroll
  for (int mf = 0; mf < 2; mf++)
#pragma unroll
    for (int nf = 0; nf < 8; nf++)
#pragma unroll
      for (int r = 0; r < 4; r++) {
        int row = qw + mf * 16 + (g << 2) + r;
        int col = h * HD_ + nf * 16 + lr;
        ao[(size_t)row * D_ + col] = f2bf(o[mf][nf][r] / l_i[mf][r]);
      }
}

// ---------- K9: wo GEMM + residual ----------
__global__ __launch_bounds__(256) void k_gemm_wo(const unsigned short* __restrict__ A,
    const unsigned short* __restrict__ Bt, const float* __restrict__ xres,
    float* __restrict__ x1) {
  alignas(16) __shared__ short As[2][128 * 32];
  alignas(16) __shared__ short Bs[2][128 * 32];
  GEMM_PRE();
  f32x4 acc[4][4];
#pragma unroll
  for (int m = 0; m < 4; m++)
#pragma unroll
    for (int n = 0; n < 4; n++) acc[m][n] = zero4;
  stage_tile(A, D_, m0, 0, (char*)As[0], tid);
  stage_tile(Bt, D_, n0, 0, (char*)Bs[0], tid);
  __syncthreads();
  int cur = 0;
  for (int k0 = 0; k0 < D_; k0 += 32) {
    if (k0 + 32 < D_) {
      stage_tile(A, D_, m0, k0 + 32, (char*)As[cur ^ 1], tid);
      stage_tile(Bt, D_, n0, k0 + 32, (char*)Bs[cur ^ 1], tid);
    }
    gemm_step((const char*)As[cur], (const char*)Bs[cur], wr, wc, g, lr, acc);
    __syncthreads();
    cur ^= 1;
  }
#pragma unroll
  for (int m = 0; m < 4; m++)
#pragma unroll
    for (int n = 0; n < 4; n++)
#pragma unroll
      for (int r = 0; r < 4; r++) {
        int row = m0 + wr + m * 16 + (g << 2) + r;
        int col = n0 + wc + n * 16 + lr;
        x1[(size_t)row * D_ + col] = acc[m][n][r] + xres[(size_t)row * D_ + col];
      }
}

// ---------- K10: RMS2 ----------
__global__ __launch_bounds__(256) void k_rms2(const float* __restrict__ x1,
                                              const float* __restrict__ ln2w,
                                              unsigned short* __restrict__ xn2) {
  int s = blockIdx.x, t = threadIdx.x;
  const float* src = x1 + (size_t)s * D_;
  float v[8];
  float ss = 0.f;
#pragma unroll
  for (int i = 0; i < 8; i++) { v[i] = src[t + i * 256]; ss += v[i] * v[i]; }
  __shared__ float red[4];
#pragma unroll
  for (int d = 32; d; d >>= 1) ss += __shfl_xor(ss, d);
  if ((t & 63) == 0) red[t >> 6] = ss;
  __syncthreads();
  ss = red[0] + red[1] + red[2] + red[3];
  float scale = rsqrtf(ss / (float)D_ + 1e-6f);
  unsigned short* dst = xn2 + (size_t)s * D_;
#pragma unroll
  for (int i = 0; i < 8; i++) {
    int c = t + i * 256;
    dst[c] = f2bf(v[i] * scale * ln2w[c]);
  }
}

// ---------- K11: fused gate/up GEMM + silu*mul epilogue ----------
__global__ __launch_bounds__(256) void k_gemm_gateup(const unsigned short* __restrict__ A,
    const unsigned short* __restrict__ Bg, const unsigned short* __restrict__ Bu,
    unsigned short* __restrict__ act) {
  alignas(16) __shared__ short As[2][128 * 32];
  alignas(16) __shared__ short Bs0[2][128 * 32];
  alignas(16) __shared__ short Bs1[2][128 * 32];
  GEMM_PRE();
  f32x4 ag[4][4], au[4][4];
#pragma unroll
  for (int m = 0; m < 4; m++)
#pragma unroll
    for (int n = 0; n < 4; n++) { ag[m][n] = zero4; au[m][n] = zero4; }
  stage_tile(A, D_, m0, 0, (char*)As[0], tid);
  stage_tile(Bg, D_, n0, 0, (char*)Bs0[0], tid);
  stage_tile(Bu, D_, n0, 0, (char*)Bs1[0], tid);
  __syncthreads();
  int cur = 0;
  for (int k0 = 0; k0 < D_; k0 += 32) {
    if (k0 + 32 < D_) {
      stage_tile(A, D_, m0, k0 + 32, (char*)As[cur ^ 1], tid);
      stage_tile(Bg, D_, n0, k0 + 32, (char*)Bs0[cur ^ 1], tid);
      stage_tile(Bu, D_, n0, k0 + 32, (char*)Bs1[cur ^ 1], tid);
    }
    gemm_step((const char*)As[cur], (const char*)Bs0[cur], wr, wc, g, lr, ag);
    gemm_step((const char*)As[cur], (const char*)Bs1[cur], wr, wc, g, lr, au);
    __syncthreads();
    cur ^= 1;
  }
#pragma unroll
  for (int m = 0; m < 4; m++)
#pragma unroll
    for (int n = 0; n < 4; n++)
#pragma unroll
      for (int r = 0; r < 4; r++) {
        int row = m0 + wr + m * 16 + (g << 2) + r;
        int col = n0 + wc + n * 16 + lr;
        float gv = ag[m][n][r], uv = au[m][n][r];
        float si = gv / (1.f + __expf(-gv));
        act[(size_t)row * I_ + col] = f2bf(si * uv);
      }
}

// ---------- K12: down GEMM + residual + sigmoid blend + scatter ----------
__global__ __launch_bounds__(256) void k_gemm_down(const unsigned short* __restrict__ A,
    const unsigned short* __restrict__ Bt, const float* __restrict__ x1,
    const float* __restrict__ x, const float* __restrict__ gate,
    const int* __restrict__ pos, float* __restrict__ out) {
  alignas(16) __shared__ short As[2][128 * 32];
  alignas(16) __shared__ short Bs[2][128 * 32];
  GEMM_PRE();
  f32x4 acc[4][4];
#pragma unroll
  for (int m = 0; m < 4; m++)
#pragma unroll
    for (int n = 0; n < 4; n++) acc[m][n] = zero4;
  stage_tile(A, I_, m0, 0, (char*)As[0], tid);
  stage_tile(Bt, I_, n0, 0, (char*)Bs[0], tid);
  __syncthreads();
  int cur = 0;
  for (int k0 = 0; k0 < I_; k0 += 32) {
    if (k0 + 32 < I_) {
      stage_tile(A, I_, m0, k0 + 32, (char*)As[cur ^ 1], tid);
      stage_tile(Bt, I_, n0, k0 + 32, (char*)Bs[cur ^ 1], tid);
    }
    gemm_step((const char*)As[cur], (const char*)Bs[cur], wr, wc, g, lr, acc);
    __syncthreads();
    cur ^= 1;
  }
#pragma unroll
  for (int m = 0; m < 4; m++)
#pragma unroll
    for (int n = 0; n < 4; n++)
#pragma unroll
      for (int r = 0; r < 4; r++) {
        int srow = m0 + wr + m * 16 + (g << 2) + r;
        int col = n0 + wc + n * 16 + lr;
        float proc = acc[m][n][r] + x1[(size_t)srow * D_ + col];
        float gt = gate[srow];
        float xv = x[(size_t)srow * D_ + col];
        int bb = srow >> 9;
        int p = pos[srow];
        out[((size_t)bb * T_ + p) * D_ + col] = gt * proc + (1.f - gt) * xv;
      }
}

extern "C" void kernel_launch(void* const* d_in, const int* in_sizes, int n_in,
                              void* d_out, int out_size, void* d_ws, size_t ws_size,
                              hipStream_t stream) {
  (void)in_sizes; (void)n_in; (void)out_size; (void)ws_size;
  const float* hidden = (const float*)d_in[0];
  const float* router_w = (const float*)d_in[1];
  const float* router_b = (const float*)d_in[2];
  const float* ln1w = (const float*)d_in[3];
  const float* ln2w = (const float*)d_in[4];
  const float* wq = (const float*)d_in[5];
  const float* bq = (const float*)d_in[6];
  const float* wk = (const float*)d_in[7];
  const float* bk = (const float*)d_in[8];
  const float* wv = (const float*)d_in[9];
  const float* bv = (const float*)d_in[10];
  const float* wo = (const float*)d_in[11];
  const float* wg = (const float*)d_in[12];
  const float* wu = (const float*)d_in[13];
  const float* wd = (const float*)d_in[14];
  float* out = (float*)d_out;

  char* ws = (char*)d_ws;
  size_t off = 0;
  auto alloc = [&](size_t bytes) {
    char* p = ws + off;
    off += (bytes + 255) & ~(size_t)255;
    return p;
  };
  unsigned short* wqkvT = (unsigned short*)alloc(3ull * D_ * D_ * 2);
  unsigned short* woT = (unsigned short*)alloc((size_t)D_ * D_ * 2);
  unsigned short* wgT = (unsigned short*)alloc((size_t)I_ * D_ * 2);
  unsigned short* wuT = (unsigned short*)alloc((size_t)I_ * D_ * 2);
  unsigned short* wdT = (unsigned short*)alloc((size_t)D_ * I_ * 2);
  float* scores = (float*)alloc((size_t)B_ * T_ * 4);
  int* pos = (int*)alloc((size_t)S_ * 4);
  float* gate = (float*)alloc((size_t)S_ * 4);
  float* x = (float*)alloc((size_t)S_ * D_ * 4);
  float* x1 = (float*)alloc((size_t)S_ * D_ * 4);
  unsigned short* xn = (unsigned short*)alloc((size_t)S_ * D_ * 2);  // reused as x1n
  float* cosb = (float*)alloc((size_t)S_ * 64 * 4);
  float* sinb = (float*)alloc((size_t)S_ * 64 * 4);
  unsigned short* qkv = (unsigned short*)alloc((size_t)S_ * D3_ * 2);  // reused as act
  unsigned short* qh = (unsigned short*)alloc((size_t)H_ * S_ * HD_ * 2);
  unsigned short* kh = (unsigned short*)alloc((size_t)H_ * S_ * HD_ * 2);
  unsigned short* vT = (unsigned short*)alloc((size_t)H_ * S_ * HD_ * 2);
  unsigned short* ao = (unsigned short*)alloc((size_t)S_ * D_ * 2);

  k_copy_scores<<<B_ * T_, 256, 0, stream>>>((const float4*)hidden, (float4*)out,
                                             (const float4*)router_w, router_b, scores);

  k_transpose<<<dim3(D_ / 32, D_ / 32), 256, 0, stream>>>(wq, wqkvT, D_, D_);
  k_transpose<<<dim3(D_ / 32, D_ / 32), 256, 0, stream>>>(wk, wqkvT + (size_t)D_ * D_, D_, D_);
  k_transpose<<<dim3(D_ / 32, D_ / 32), 256, 0, stream>>>(wv, wqkvT + 2ull * D_ * D_, D_, D_);
  k_transpose<<<dim3(D_ / 32, D_ / 32), 256, 0, stream>>>(wo, woT, D_, D_);
  k_transpose<<<dim3(I_ / 32, D_ / 32), 256, 0, stream>>>(wg, wgT, D_, I_);
  k_transpose<<<dim3(I_ / 32, D_ / 32), 256, 0, stream>>>(wu, wuT, D_, I_);
  k_transpose<<<dim3(D_ / 32, I_ / 32), 256, 0, stream>>>(wd, wdT, I_, D_);

  k_topk<<<B_, 1024, 0, stream>>>(scores, pos);
  k_gather<<<S_, 256, 0, stream>>>(hidden, pos, scores, ln1w, x, xn, gate, cosb, sinb);

  k_gemm_qkv<<<dim3(S_ / 128, D3_ / 128), 256, 0, stream>>>(xn, wqkvT, qkv, bq, bk, bv);
  k_rope<<<dim3(S_ / 64, H_), 256, 0, stream>>>(qkv, cosb, sinb, qh, kh, vT);
  k_attn<<<dim3(S_ / 128, H_), 256, 0, stream>>>(qh, kh, vT, ao);
  k_gemm_wo<<<dim3(S_ / 128, D_ / 128), 256, 0, stream>>>(ao, woT, x, x1);
  k_rms2<<<S_, 256, 0, stream>>>(x1, ln2w, xn);
  k_gemm_gateup<<<dim3(S_ / 128, I_ / 128), 256, 0, stream>>>(xn, wgT, wuT, qkv);
  k_gemm_down<<<dim3(S_ / 128, D_ / 128), 256, 0, stream>>>(qkv, wdT, x1, x, gate, pos, out);
}

// Round 4
// 725.103 us; speedup vs baseline: 1.1227x; 1.0502x over previous
//
#include <hip/hip_runtime.h>
#include <stdint.h>

#define B_ 4
#define T_ 2048
#define D_ 2048
#define H_ 16
#define HD_ 128
#define I_ 5632
#define K_ 512
#define S_ 2048
#define D3_ (3 * D_)

typedef float f32x4 __attribute__((ext_vector_type(4)));
typedef short s16x8 __attribute__((ext_vector_type(8)));
typedef __bf16 bf16x8 __attribute__((ext_vector_type(8)));

// ---------- mfma wrapper robust to builtin operand type (short8 vs bf16x8) ----------
template <typename V>
__device__ __forceinline__ auto mfma_try(V a, V b, f32x4 c, int)
    -> decltype(__builtin_amdgcn_mfma_f32_16x16x32_bf16(a, b, c, 0, 0, 0)) {
  return __builtin_amdgcn_mfma_f32_16x16x32_bf16(a, b, c, 0, 0, 0);
}
template <typename V>
__device__ __forceinline__ f32x4 mfma_try(V a, V b, f32x4 c, long) {
  return __builtin_amdgcn_mfma_f32_16x16x32_bf16(
      __builtin_bit_cast(bf16x8, a), __builtin_bit_cast(bf16x8, b), c, 0, 0, 0);
}
__device__ __forceinline__ f32x4 mfma_bf16(s16x8 a, s16x8 b, f32x4 c) {
  return mfma_try(a, b, c, 0);
}

__device__ __forceinline__ void gl_lds16(const void* g, void* l) {
  __builtin_amdgcn_global_load_lds((const __attribute__((address_space(1))) void*)g,
                                   (__attribute__((address_space(3))) void*)l, 16, 0, 0);
}

__device__ __forceinline__ unsigned short f2bf(float f) {
  unsigned u = __float_as_uint(f);
  u += 0x7FFFu + ((u >> 16) & 1);
  return (unsigned short)(u >> 16);
}
__device__ __forceinline__ float bf2f(unsigned short s) {
  return __uint_as_float(((unsigned)s) << 16);
}

// ---------- K1: copy hidden -> out, fused with router scores ----------
__global__ __launch_bounds__(256) void k_copy_scores(const float4* __restrict__ hid,
                                                     float4* __restrict__ dst,
                                                     const float4* __restrict__ rw,
                                                     const float* __restrict__ rb,
                                                     float* __restrict__ scores) {
  int row = blockIdx.x, t = threadIdx.x;
  const float4* hr = hid + (size_t)row * (D_ / 4);
  float4* dr = dst + (size_t)row * (D_ / 4);
  float acc = 0.f;
#pragma unroll
  for (int i = 0; i < 2; i++) {
    float4 v = hr[t + i * 256];
    dr[t + i * 256] = v;
    float4 w = rw[t + i * 256];
    acc += v.x * w.x + v.y * w.y + v.z * w.z + v.w * w.w;
  }
#pragma unroll
  for (int d = 32; d; d >>= 1) acc += __shfl_xor(acc, d);
  __shared__ float red[4];
  if ((t & 63) == 0) red[t >> 6] = acc;
  __syncthreads();
  if (t == 0) scores[row] = red[0] + red[1] + red[2] + red[3] + rb[0];
}

// ---------- K3: exact top-k (bitonic, matches jax.lax.top_k tie-break) ----------
__global__ __launch_bounds__(1024) void k_topk(const float* __restrict__ scores,
                                               int* __restrict__ pos) {
  __shared__ unsigned long long keys[T_];
  __shared__ int sidx[K_];
  int b = blockIdx.x, t = threadIdx.x;
  for (int i = t; i < T_; i += 1024) {
    unsigned u = __float_as_uint(scores[b * T_ + i]);
    u = (u & 0x80000000u) ? ~u : (u | 0x80000000u);
    keys[i] = ((unsigned long long)u << 32) | (unsigned)(~(unsigned)i);
  }
  __syncthreads();
  for (int k = 2; k <= T_; k <<= 1)
    for (int j = k >> 1; j > 0; j >>= 1) {
      for (int i = t; i < T_; i += 1024) {
        int l = i ^ j;
        if (l > i) {
          unsigned long long a = keys[i], c = keys[l];
          bool desc = ((i & k) == 0);
          if (desc ? (a < c) : (a > c)) { keys[i] = c; keys[l] = a; }
        }
      }
      __syncthreads();
    }
  if (t < K_) sidx[t] = (int)(~(unsigned)(keys[t] & 0xFFFFFFFFull));
  __syncthreads();
  for (int k = 2; k <= K_; k <<= 1)
    for (int j = k >> 1; j > 0; j >>= 1) {
      if (t < K_) {
        int i = t, l = i ^ j;
        if (l > i && l < K_) {
          int a = sidx[i], c = sidx[l];
          bool asc = ((i & k) == 0);
          if (asc ? (a > c) : (a < c)) { sidx[i] = c; sidx[l] = a; }
        }
      }
      __syncthreads();
    }
  if (t < K_) pos[b * K_ + t] = sidx[t];
}

// ---------- K4: gather + RMS1 + gate + rope tables ----------
__global__ __launch_bounds__(256) void k_gather(const float* __restrict__ hidden,
    const int* __restrict__ pos, const float* __restrict__ scores,
    const float* __restrict__ ln1w, float* __restrict__ x,
    unsigned short* __restrict__ xn, float* __restrict__ gate,
    float* __restrict__ cosb, float* __restrict__ sinb) {
  int s = blockIdx.x, t = threadIdx.x;
  int b = s >> 9, p = pos[s];
  const float* src = hidden + ((size_t)b * T_ + p) * D_;
  float v[8];
  float ss = 0.f;
#pragma unroll
  for (int i = 0; i < 8; i++) { v[i] = src[t + i * 256]; ss += v[i] * v[i]; }
  __shared__ float red[4];
#pragma unroll
  for (int d = 32; d; d >>= 1) ss += __shfl_xor(ss, d);
  if ((t & 63) == 0) red[t >> 6] = ss;
  __syncthreads();
  ss = red[0] + red[1] + red[2] + red[3];
  float scale = rsqrtf(ss / (float)D_ + 1e-6f);
  float* xd = x + (size_t)s * D_;
  unsigned short* xnd = xn + (size_t)s * D_;
#pragma unroll
  for (int i = 0; i < 8; i++) {
    int c = t + i * 256;
    xd[c] = v[i];
    xnd[c] = f2bf(v[i] * scale * ln1w[c]);
  }
  if (t == 0) gate[s] = 1.f / (1.f + expf(-scores[b * T_ + p]));
  if (t < 64) {
    float invf = powf(10000.0f, -(float)t / 64.0f);
    float f = (float)p * invf;
    cosb[s * 64 + t] = cosf(f);
    sinb[s * 64 + t] = sinf(f);
  }
}

// ---------- K5: transpose + f32->bf16 (weights to Bt layout) ----------
__global__ __launch_bounds__(256) void k_transpose(const float* __restrict__ src,
                                                   unsigned short* __restrict__ dst,
                                                   int R, int C) {
  __shared__ float tile[32][33];
  int tx = threadIdx.x & 31, ty = threadIdx.x >> 5;
  int c0 = blockIdx.x * 32, r0 = blockIdx.y * 32;
#pragma unroll
  for (int i = 0; i < 4; i++) {
    int r = ty + i * 8;
    tile[r][tx] = src[(size_t)(r0 + r) * C + c0 + tx];
  }
  __syncthreads();
#pragma unroll
  for (int i = 0; i < 4; i++) {
    int r = ty + i * 8;
    dst[(size_t)(c0 + r) * R + r0 + tx] = f2bf(tile[tx][r]);
  }
}

// ======================================================================
// 8-wave 256-wide GEMM template (BK=32, dbuf, counted vmcnt, T2 swizzle)
// Schedule per K-tile t (buffer b = t&1):
//   vmcnt(4) [drains tile t's 4 loads] -> barrier
//   ds_read ALL frags of tile t -> explicit lgkmcnt(0) -> barrier
//   [all waves' reads of buf b complete => safe] stage tile t+2 into buf b
//   setprio(1) 32x MFMA setprio(0)
// Loads stay in flight across barriers; vmcnt(0) only on the last tile.
// LDS rows are 64B; swizzle involution: byte ^= ((row&3)<<4), applied to
// the GLOBAL source (gl_lds dest must be linear, m104/m173) and the read.
// ======================================================================
__device__ __forceinline__ void stage16k(const unsigned short* __restrict__ g, int ldK,
                                         int row0, int k0, char* lds, int tid) {
#pragma unroll
  for (int c = 0; c < 2; c++) {
    int off = c * 8192 + tid * 16;
    int row = off >> 6;
    int cb = (off & 63) ^ ((row & 3) << 4);
    gl_lds16(g + (size_t)(row0 + row) * ldK + k0 + (cb >> 1), lds + off);
  }
}
__device__ __forceinline__ void stage8k(const unsigned short* __restrict__ g, int ldK,
                                        int row0, int k0, char* lds, int tid) {
  int off = tid * 16;
  int row = off >> 6;
  int cb = (off & 63) ^ ((row & 3) << 4);
  gl_lds16(g + (size_t)(row0 + row) * ldK + k0 + (cb >> 1), lds + off);
}
__device__ __forceinline__ s16x8 ldfrag(const char* base, int row, int g) {
  return *(const s16x8*)(base + row * 64 + ((g * 16) ^ ((row & 3) << 4)));
}

// ---------- K6: fused QKV GEMM, 256x256 tile, 8 waves, bias epilogue ----------
__global__ __launch_bounds__(512, 2) void k_gemm_qkv8(const unsigned short* __restrict__ A,
    const unsigned short* __restrict__ Bt, unsigned short* __restrict__ C,
    const float* __restrict__ bq, const float* __restrict__ bk,
    const float* __restrict__ bv) {
  alignas(16) __shared__ short As[2][256 * 32];
  alignas(16) __shared__ short Bs[2][256 * 32];
  int tid = threadIdx.x;
  int lane = tid & 63, g = lane >> 4, lr = lane & 15;
  int wid = tid >> 6, wm = wid >> 2, wn = wid & 3;
  int m0 = blockIdx.x * 256, n0 = blockIdx.y * 256;
  f32x4 zero4 = {0.f, 0.f, 0.f, 0.f};
  f32x4 acc[8][4];
#pragma unroll
  for (int m = 0; m < 8; m++)
#pragma unroll
    for (int n = 0; n < 4; n++) acc[m][n] = zero4;
  const int nkt = D_ / 32;
  stage16k(A, D_, m0, 0, (char*)As[0], tid);
  stage16k(Bt, D_, n0, 0, (char*)Bs[0], tid);
  stage16k(A, D_, m0, 32, (char*)As[1], tid);
  stage16k(Bt, D_, n0, 32, (char*)Bs[1], tid);
  int arow = wm * 128 + lr;
  int brow = wn * 64 + lr;
  for (int t = 0; t < nkt; t++) {
    int b = t & 1;
    const char* Ab = (const char*)As[b];
    const char* Bb = (const char*)Bs[b];
    if (t + 1 < nkt) asm volatile("s_waitcnt vmcnt(4)" ::: "memory");
    else             asm volatile("s_waitcnt vmcnt(0)" ::: "memory");
    __builtin_amdgcn_s_barrier();
    s16x8 af[8], bf4[4];
#pragma unroll
    for (int i = 0; i < 4; i++) af[i] = ldfrag(Ab, arow + i * 16, g);
#pragma unroll
    for (int i = 0; i < 4; i++) af[i + 4] = ldfrag(Ab, arow + 64 + i * 16, g);
#pragma unroll
    for (int i = 0; i < 4; i++) bf4[i] = ldfrag(Bb, brow + i * 16, g);
    asm volatile("s_waitcnt lgkmcnt(0)" ::: "memory");
    __builtin_amdgcn_s_barrier();
    if (t + 2 < nkt) {
      stage16k(A, D_, m0, (t + 2) * 32, (char*)As[b], tid);
      stage16k(Bt, D_, n0, (t + 2) * 32, (char*)Bs[b], tid);
    }
    __builtin_amdgcn_s_setprio(1);
#pragma unroll
    for (int m = 0; m < 8; m++)
#pragma unroll
      for (int n = 0; n < 4; n++) acc[m][n] = mfma_bf16(af[m], bf4[n], acc[m][n]);
    __builtin_amdgcn_s_setprio(0);
  }
#pragma unroll
  for (int m = 0; m < 8; m++)
#pragma unroll
    for (int n = 0; n < 4; n++)
#pragma unroll
      for (int r = 0; r < 4; r++) {
        int row = m0 + wm * 128 + m * 16 + (g << 2) + r;
        int col = n0 + wn * 64 + n * 16 + lr;
        float bias = (col < D_) ? bq[col] : ((col < 2 * D_) ? bk[col - D_] : bv[col - 2 * D_]);
        C[(size_t)row * D3_ + col] = f2bf(acc[m][n][r] + bias);
      }
}

// ---------- K11: fused gate/up GEMM, 256x(128+128) tile, 8 waves, silu*mul ----------
__global__ __launch_bounds__(512, 2) void k_gemm_gup8(const unsigned short* __restrict__ A,
    const unsigned short* __restrict__ Bg, const unsigned short* __restrict__ Bu,
    unsigned short* __restrict__ act) {
  alignas(16) __shared__ short As[2][256 * 32];
  alignas(16) __shared__ short Bgs[2][128 * 32];
  alignas(16) __shared__ short Bus[2][128 * 32];
  int tid = threadIdx.x;
  int lane = tid & 63, g = lane >> 4, lr = lane & 15;
  int wid = tid >> 6, wm = wid >> 1, wn = wid & 1;
  int m0 = blockIdx.x * 256, n0 = blockIdx.y * 128;
  f32x4 zero4 = {0.f, 0.f, 0.f, 0.f};
  f32x4 ag[4][4], au[4][4];
#pragma unroll
  for (int m = 0; m < 4; m++)
#pragma unroll
    for (int n = 0; n < 4; n++) { ag[m][n] = zero4; au[m][n] = zero4; }
  const int nkt = D_ / 32;
  stage16k(A, D_, m0, 0, (char*)As[0], tid);
  stage8k(Bg, D_, n0, 0, (char*)Bgs[0], tid);
  stage8k(Bu, D_, n0, 0, (char*)Bus[0], tid);
  stage16k(A, D_, m0, 32, (char*)As[1], tid);
  stage8k(Bg, D_, n0, 32, (char*)Bgs[1], tid);
  stage8k(Bu, D_, n0, 32, (char*)Bus[1], tid);
  int arow = wm * 64 + lr;
  int brow = wn * 64 + lr;
  for (int t = 0; t < nkt; t++) {
    int b = t & 1;
    const char* Ab = (const char*)As[b];
    const char* Bgb = (const char*)Bgs[b];
    const char* Bub = (const char*)Bus[b];
    if (t + 1 < nkt) asm volatile("s_waitcnt vmcnt(4)" ::: "memory");
    else             asm volatile("s_waitcnt vmcnt(0)" ::: "memory");
    __builtin_amdgcn_s_barrier();
    s16x8 af[4], bg4[4], bu4[4];
#pragma unroll
    for (int i = 0; i < 4; i++) af[i] = ldfrag(Ab, arow + i * 16, g);
#pragma unroll
    for (int i = 0; i < 4; i++) bg4[i] = ldfrag(Bgb, brow + i * 16, g);
#pragma unroll
    for (int i = 0; i < 4; i++) bu4[i] = ldfrag(Bub, brow + i * 16, g);
    asm volatile("s_waitcnt lgkmcnt(0)" ::: "memory");
    __builtin_amdgcn_s_barrier();
    if (t + 2 < nkt) {
      stage16k(A, D_, m0, (t + 2) * 32, (char*)As[b], tid);
      stage8k(Bg, D_, n0, (t + 2) * 32, (char*)Bgs[b], tid);
      stage8k(Bu, D_, n0, (t + 2) * 32, (char*)Bus[b], tid);
    }
    __builtin_amdgcn_s_setprio(1);
#pragma unroll
    for (int m = 0; m < 4; m++)
#pragma unroll
      for (int n = 0; n < 4; n++) {
        ag[m][n] = mfma_bf16(af[m], bg4[n], ag[m][n]);
        au[m][n] = mfma_bf16(af[m], bu4[n], au[m][n]);
      }
    __builtin_amdgcn_s_setprio(0);
  }
#pragma unroll
  for (int m = 0; m < 4; m++)
#pragma unroll
    for (int n = 0; n < 4; n++)
#pragma unroll
      for (int r = 0; r < 4; r++) {
        int row = m0 + wm * 64 + m * 16 + (g << 2) + r;
        int col = n0 + wn * 64 + n * 16 + lr;
        float gv = ag[m][n][r], uv = au[m][n][r];
        float si = gv / (1.f + __expf(-gv));
        act[(size_t)row * I_ + col] = f2bf(si * uv);
      }
}

// ---------- GEMM building blocks (128x128 tile, BK=32, dbuf 2-phase) ----------
__device__ __forceinline__ void stage_tile(const unsigned short* __restrict__ gbase,
                                           int ldK, int row0, int k0, char* lds, int tid) {
  int w = tid >> 6, lane = tid & 63;
#pragma unroll
  for (int p = 0; p < 2; p++) {
    int ldsoff = p * 4096 + w * 1024;
    int boff = ldsoff + lane * 16;
    int row = boff >> 6;
    int ke = (boff & 63) >> 1;
    gl_lds16(gbase + (size_t)(row0 + row) * ldK + k0 + ke, lds + ldsoff);
  }
}

__device__ __forceinline__ void gemm_step(const char* As, const char* Bs, int wr, int wc,
                                          int g, int lr, f32x4 acc[4][4]) {
  s16x8 af[4], bf4[4];
#pragma unroll
  for (int i = 0; i < 4; i++)
    af[i] = *(const s16x8*)(As + ((wr + i * 16 + lr) << 6) + (g << 4));
#pragma unroll
  for (int i = 0; i < 4; i++)
    bf4[i] = *(const s16x8*)(Bs + ((wc + i * 16 + lr) << 6) + (g << 4));
#pragma unroll
  for (int m = 0; m < 4; m++)
#pragma unroll
    for (int n = 0; n < 4; n++) acc[m][n] = mfma_bf16(af[m], bf4[n], acc[m][n]);
}

#define GEMM_PRE()                                                     \
  int tid = threadIdx.x;                                               \
  int w = tid >> 6, lane = tid & 63, g = lane >> 4, lr = lane & 15;    \
  int wr = (w >> 1) * 64, wc = (w & 1) * 64;                           \
  int m0 = blockIdx.x * 128, n0 = blockIdx.y * 128;                    \
  f32x4 zero4 = {0.f, 0.f, 0.f, 0.f};                                  \
  (void)lane;

// ---------- K7: RoPE + head relayout (q,k row-major per head; v transposed) ----------
__global__ __launch_bounds__(256) void k_rope(const unsigned short* __restrict__ qkv,
    const float* __restrict__ cosb, const float* __restrict__ sinb,
    unsigned short* __restrict__ qh, unsigned short* __restrict__ kh,
    unsigned short* __restrict__ vT) {
  int s0 = blockIdx.x * 64;
  int h = blockIdx.y;
  int t = threadIdx.x;
#pragma unroll
  for (int i = 0; i < 16; i++) {
    int flat = t + i * 256;
    int r = flat >> 6, dp = flat & 63;
    int s = s0 + r;
    float c = cosb[s * 64 + dp], sn = sinb[s * 64 + dp];
    const unsigned short* qrow = qkv + (size_t)s * D3_ + h * HD_;
    float q1 = bf2f(qrow[dp]), q2 = bf2f(qrow[dp + 64]);
    unsigned short* qdst = qh + ((size_t)h * S_ + s) * HD_;
    qdst[dp] = f2bf(q1 * c - q2 * sn);
    qdst[dp + 64] = f2bf(q2 * c + q1 * sn);
    const unsigned short* krow = qrow + D_;
    float k1 = bf2f(krow[dp]), k2 = bf2f(krow[dp + 64]);
    unsigned short* kdst = kh + ((size_t)h * S_ + s) * HD_;
    kdst[dp] = f2bf(k1 * c - k2 * sn);
    kdst[dp + 64] = f2bf(k2 * c + k1 * sn);
  }
  __shared__ unsigned short vt[128][66];
#pragma unroll
  for (int i = 0; i < 32; i++) {
    int flat = t + i * 256;
    int r = flat >> 7, d = flat & 127;
    vt[d][r] = qkv[(size_t)(s0 + r) * D3_ + 2 * D_ + h * HD_ + d];
  }
  __syncthreads();
#pragma unroll
  for (int i = 0; i < 32; i++) {
    int flat = t + i * 256;
    int d = flat >> 6, sc = flat & 63;
    vT[((size_t)h * HD_ + d) * S_ + s0 + sc] = vt[d][sc];
  }
}

// ---------- K8: flash attention over packed sequence (causal on S) ----------
__global__ __launch_bounds__(256) void k_attn(const unsigned short* __restrict__ qh,
                                              const unsigned short* __restrict__ kh,
                                              const unsigned short* __restrict__ vT,
                                              unsigned short* __restrict__ ao) {
  alignas(16) __shared__ short Ks[64 * 128];   // [kv][d]
  alignas(16) __shared__ short Vs[128 * 64];   // [d][kv]
  alignas(16) __shared__ short Ps[4][32 * 64]; // per-wave P
  int h = blockIdx.y;
  int q0 = blockIdx.x * 128;
  int tid = threadIdx.x, w = tid >> 6, lane = tid & 63, g = lane >> 4, lr = lane & 15;
  size_t hbase = (size_t)h * S_ * HD_;
  int qw = q0 + w * 32;
  s16x8 qf[2][4];
#pragma unroll
  for (int mf = 0; mf < 2; mf++)
#pragma unroll
    for (int ks = 0; ks < 4; ks++)
      qf[mf][ks] = *(const s16x8*)&qh[hbase + (size_t)(qw + mf * 16 + lr) * HD_ + ks * 32 + g * 8];
  f32x4 o[2][8];
  f32x4 zero4 = {0.f, 0.f, 0.f, 0.f};
#pragma unroll
  for (int mf = 0; mf < 2; mf++)
#pragma unroll
    for (int nf = 0; nf < 8; nf++) o[mf][nf] = zero4;
  float m_i[2][4], l_i[2][4];
#pragma unroll
  for (int mf = 0; mf < 2; mf++)
#pragma unroll
    for (int r = 0; r < 4; r++) { m_i[mf][r] = -1e30f; l_i[mf][r] = 0.f; }
  const float sc = 0.08838834764831843f;  // 1/sqrt(128)
  int ktiles = (q0 + 128) >> 6;
  for (int kt = 0; kt < ktiles; kt++) {
#pragma unroll
    for (int p = 0; p < 4; p++) {
      int ldsoff = p * 4096 + w * 1024;
      int boff = ldsoff + lane * 16;
      int krow = boff >> 8, kcolb = boff & 255;
      gl_lds16(kh + hbase + (size_t)(kt * 64 + krow) * HD_ + (kcolb >> 1), (char*)Ks + ldsoff);
      int vrow = boff >> 7, vcol = (boff & 127) >> 1;
      gl_lds16(vT + hbase + (size_t)vrow * S_ + kt * 64 + vcol, (char*)Vs + ldsoff);
    }
    __syncthreads();
    bool active = (kt * 64) <= (qw + 31);
    if (active) {
      f32x4 sacc[2][4];
#pragma unroll
      for (int mf = 0; mf < 2; mf++)
#pragma unroll
        for (int nf = 0; nf < 4; nf++) sacc[mf][nf] = zero4;
#pragma unroll
      for (int ks = 0; ks < 4; ks++) {
        s16x8 kf[4];
#pragma unroll
        for (int nf = 0; nf < 4; nf++)
          kf[nf] = *(const s16x8*)((const char*)Ks + ((nf * 16 + lr) << 8) + (ks << 6) + (g << 4));
#pragma unroll
        for (int mf = 0; mf < 2; mf++)
#pragma unroll
          for (int nf = 0; nf < 4; nf++)
            sacc[mf][nf] = mfma_bf16(qf[mf][ks], kf[nf], sacc[mf][nf]);
      }
#pragma unroll
      for (int mf = 0; mf < 2; mf++)
#pragma unroll
        for (int r = 0; r < 4; r++) {
          int qrow = qw + mf * 16 + (g << 2) + r;
          float pv[4];
          float mx = -1e30f;
#pragma unroll
          for (int nf = 0; nf < 4; nf++) {
            int kc = kt * 64 + nf * 16 + lr;
            float vv = sacc[mf][nf][r] * sc;
            vv = (kc <= qrow) ? vv : -1e30f;
            pv[nf] = vv;
            mx = fmaxf(mx, vv);
          }
#pragma unroll
          for (int d = 1; d < 16; d <<= 1) mx = fmaxf(mx, __shfl_xor(mx, d));
          float mold = m_i[mf][r], mnew = fmaxf(mold, mx);
          float corr = __expf(mold - mnew);
          float ssum = 0.f;
#pragma unroll
          for (int nf = 0; nf < 4; nf++) {
            float pe = __expf(pv[nf] - mnew);
            Ps[w][(mf * 16 + (g << 2) + r) * 64 + nf * 16 + lr] = (short)f2bf(pe);
            ssum += pe;
          }
#pragma unroll
          for (int d = 1; d < 16; d <<= 1) ssum += __shfl_xor(ssum, d);
          l_i[mf][r] = l_i[mf][r] * corr + ssum;
          m_i[mf][r] = mnew;
#pragma unroll
          for (int nf = 0; nf < 8; nf++) o[mf][nf][r] *= corr;
        }
      // Ps is per-wave: no __syncthreads needed between write and PV read.
#pragma unroll
      for (int ks = 0; ks < 2; ks++) {
        s16x8 pa[2];
#pragma unroll
        for (int mf = 0; mf < 2; mf++)
          pa[mf] = *(const s16x8*)((const char*)&Ps[w][0] + ((mf * 16 + lr) << 7) + (ks << 6) + (g << 4));
#pragma unroll
        for (int nf = 0; nf < 8; nf++) {
          s16x8 vb = *(const s16x8*)((const char*)Vs + ((nf * 16 + lr) << 7) + (ks << 6) + (g << 4));
#pragma unroll
          for (int mf = 0; mf < 2; mf++) o[mf][nf] = mfma_bf16(pa[mf], vb, o[mf][nf]);
        }
      }
    }
    __syncthreads();
  }
#pragma unroll
  for (int mf = 0; mf < 2; mf++)
#pragma unroll
    for (int nf = 0; nf < 8; nf++)
#pragma unroll
      for (int r = 0; r < 4; r++) {
        int row = qw + mf * 16 + (g << 2) + r;
        int col = h * HD_ + nf * 16 + lr;
        ao[(size_t)row * D_ + col] = f2bf(o[mf][nf][r] / l_i[mf][r]);
      }
}

// ---------- K9: wo GEMM + residual ----------
__global__ __launch_bounds__(256) void k_gemm_wo(const unsigned short* __restrict__ A,
    const unsigned short* __restrict__ Bt, const float* __restrict__ xres,
    float* __restrict__ x1) {
  alignas(16) __shared__ short As[2][128 * 32];
  alignas(16) __shared__ short Bs[2][128 * 32];
  GEMM_PRE();
  f32x4 acc[4][4];
#pragma unroll
  for (int m = 0; m < 4; m++)
#pragma unroll
    for (int n = 0; n < 4; n++) acc[m][n] = zero4;
  stage_tile(A, D_, m0, 0, (char*)As[0], tid);
  stage_tile(Bt, D_, n0, 0, (char*)Bs[0], tid);
  __syncthreads();
  int cur = 0;
  for (int k0 = 0; k0 < D_; k0 += 32) {
    if (k0 + 32 < D_) {
      stage_tile(A, D_, m0, k0 + 32, (char*)As[cur ^ 1], tid);
      stage_tile(Bt, D_, n0, k0 + 32, (char*)Bs[cur ^ 1], tid);
    }
    gemm_step((const char*)As[cur], (const char*)Bs[cur], wr, wc, g, lr, acc);
    __syncthreads();
    cur ^= 1;
  }
#pragma unroll
  for (int m = 0; m < 4; m++)
#pragma unroll
    for (int n = 0; n < 4; n++)
#pragma unroll
      for (int r = 0; r < 4; r++) {
        int row = m0 + wr + m * 16 + (g << 2) + r;
        int col = n0 + wc + n * 16 + lr;
        x1[(size_t)row * D_ + col] = acc[m][n][r] + xres[(size_t)row * D_ + col];
      }
}

// ---------- K10: RMS2 ----------
__global__ __launch_bounds__(256) void k_rms2(const float* __restrict__ x1,
                                              const float* __restrict__ ln2w,
                                              unsigned short* __restrict__ xn2) {
  int s = blockIdx.x, t = threadIdx.x;
  const float* src = x1 + (size_t)s * D_;
  float v[8];
  float ss = 0.f;
#pragma unroll
  for (int i = 0; i < 8; i++) { v[i] = src[t + i * 256]; ss += v[i] * v[i]; }
  __shared__ float red[4];
#pragma unroll
  for (int d = 32; d; d >>= 1) ss += __shfl_xor(ss, d);
  if ((t & 63) == 0) red[t >> 6] = ss;
  __syncthreads();
  ss = red[0] + red[1] + red[2] + red[3];
  float scale = rsqrtf(ss / (float)D_ + 1e-6f);
  unsigned short* dst = xn2 + (size_t)s * D_;
#pragma unroll
  for (int i = 0; i < 8; i++) {
    int c = t + i * 256;
    dst[c] = f2bf(v[i] * scale * ln2w[c]);
  }
}

// ---------- K12: down GEMM + residual + sigmoid blend + scatter ----------
__global__ __launch_bounds__(256) void k_gemm_down(const unsigned short* __restrict__ A,
    const unsigned short* __restrict__ Bt, const float* __restrict__ x1,
    const float* __restrict__ x, const float* __restrict__ gate,
    const int* __restrict__ pos, float* __restrict__ out) {
  alignas(16) __shared__ short As[2][128 * 32];
  alignas(16) __shared__ short Bs[2][128 * 32];
  GEMM_PRE();
  f32x4 acc[4][4];
#pragma unroll
  for (int m = 0; m < 4; m++)
#pragma unroll
    for (int n = 0; n < 4; n++) acc[m][n] = zero4;
  stage_tile(A, I_, m0, 0, (char*)As[0], tid);
  stage_tile(Bt, I_, n0, 0, (char*)Bs[0], tid);
  __syncthreads();
  int cur = 0;
  for (int k0 = 0; k0 < I_; k0 += 32) {
    if (k0 + 32 < I_) {
      stage_tile(A, I_, m0, k0 + 32, (char*)As[cur ^ 1], tid);
      stage_tile(Bt, I_, n0, k0 + 32, (char*)Bs[cur ^ 1], tid);
    }
    gemm_step((const char*)As[cur], (const char*)Bs[cur], wr, wc, g, lr, acc);
    __syncthreads();
    cur ^= 1;
  }
#pragma unroll
  for (int m = 0; m < 4; m++)
#pragma unroll
    for (int n = 0; n < 4; n++)
#pragma unroll
      for (int r = 0; r < 4; r++) {
        int srow = m0 + wr + m * 16 + (g << 2) + r;
        int col = n0 + wc + n * 16 + lr;
        float proc = acc[m][n][r] + x1[(size_t)srow * D_ + col];
        float gt = gate[srow];
        float xv = x[(size_t)srow * D_ + col];
        int bb = srow >> 9;
        int p = pos[srow];
        out[((size_t)bb * T_ + p) * D_ + col] = gt * proc + (1.f - gt) * xv;
      }
}

extern "C" void kernel_launch(void* const* d_in, const int* in_sizes, int n_in,
                              void* d_out, int out_size, void* d_ws, size_t ws_size,
                              hipStream_t stream) {
  (void)in_sizes; (void)n_in; (void)out_size; (void)ws_size;
  const float* hidden = (const float*)d_in[0];
  const float* router_w = (const float*)d_in[1];
  const float* router_b = (const float*)d_in[2];
  const float* ln1w = (const float*)d_in[3];
  const float* ln2w = (const float*)d_in[4];
  const float* wq = (const float*)d_in[5];
  const float* bq = (const float*)d_in[6];
  const float* wk = (const float*)d_in[7];
  const float* bk = (const float*)d_in[8];
  const float* wv = (const float*)d_in[9];
  const float* bv = (const float*)d_in[10];
  const float* wo = (const float*)d_in[11];
  const float* wg = (const float*)d_in[12];
  const float* wu = (const float*)d_in[13];
  const float* wd = (const float*)d_in[14];
  float* out = (float*)d_out;

  char* ws = (char*)d_ws;
  size_t off = 0;
  auto alloc = [&](size_t bytes) {
    char* p = ws + off;
    off += (bytes + 255) & ~(size_t)255;
    return p;
  };
  unsigned short* wqkvT = (unsigned short*)alloc(3ull * D_ * D_ * 2);
  unsigned short* woT = (unsigned short*)alloc((size_t)D_ * D_ * 2);
  unsigned short* wgT = (unsigned short*)alloc((size_t)I_ * D_ * 2);
  unsigned short* wuT = (unsigned short*)alloc((size_t)I_ * D_ * 2);
  unsigned short* wdT = (unsigned short*)alloc((size_t)D_ * I_ * 2);
  float* scores = (float*)alloc((size_t)B_ * T_ * 4);
  int* pos = (int*)alloc((size_t)S_ * 4);
  float* gate = (float*)alloc((size_t)S_ * 4);
  float* x = (float*)alloc((size_t)S_ * D_ * 4);
  float* x1 = (float*)alloc((size_t)S_ * D_ * 4);
  unsigned short* xn = (unsigned short*)alloc((size_t)S_ * D_ * 2);  // reused as x1n
  float* cosb = (float*)alloc((size_t)S_ * 64 * 4);
  float* sinb = (float*)alloc((size_t)S_ * 64 * 4);
  unsigned short* qkv = (unsigned short*)alloc((size_t)S_ * D3_ * 2);  // reused as act
  unsigned short* qh = (unsigned short*)alloc((size_t)H_ * S_ * HD_ * 2);
  unsigned short* kh = (unsigned short*)alloc((size_t)H_ * S_ * HD_ * 2);
  unsigned short* vT = (unsigned short*)alloc((size_t)H_ * S_ * HD_ * 2);
  unsigned short* ao = (unsigned short*)alloc((size_t)S_ * D_ * 2);

  k_copy_scores<<<B_ * T_, 256, 0, stream>>>((const float4*)hidden, (float4*)out,
                                             (const float4*)router_w, router_b, scores);

  k_transpose<<<dim3(D_ / 32, D_ / 32), 256, 0, stream>>>(wq, wqkvT, D_, D_);
  k_transpose<<<dim3(D_ / 32, D_ / 32), 256, 0, stream>>>(wk, wqkvT + (size_t)D_ * D_, D_, D_);
  k_transpose<<<dim3(D_ / 32, D_ / 32), 256, 0, stream>>>(wv, wqkvT + 2ull * D_ * D_, D_, D_);
  k_transpose<<<dim3(D_ / 32, D_ / 32), 256, 0, stream>>>(wo, woT, D_, D_);
  k_transpose<<<dim3(I_ / 32, D_ / 32), 256, 0, stream>>>(wg, wgT, D_, I_);
  k_transpose<<<dim3(I_ / 32, D_ / 32), 256, 0, stream>>>(wu, wuT, D_, I_);
  k_transpose<<<dim3(D_ / 32, I_ / 32), 256, 0, stream>>>(wd, wdT, I_, D_);

  k_topk<<<B_, 1024, 0, stream>>>(scores, pos);
  k_gather<<<S_, 256, 0, stream>>>(hidden, pos, scores, ln1w, x, xn, gate, cosb, sinb);

  k_gemm_qkv8<<<dim3(S_ / 256, D3_ / 256), 512, 0, stream>>>(xn, wqkvT, qkv, bq, bk, bv);
  k_rope<<<dim3(S_ / 64, H_), 256, 0, stream>>>(qkv, cosb, sinb, qh, kh, vT);
  k_attn<<<dim3(S_ / 128, H_), 256, 0, stream>>>(qh, kh, vT, ao);
  k_gemm_wo<<<dim3(S_ / 128, D_ / 128), 256, 0, stream>>>(ao, woT, x, x1);
  k_rms2<<<S_, 256, 0, stream>>>(x1, ln2w, xn);
  k_gemm_gup8<<<dim3(S_ / 256, I_ / 128), 512, 0, stream>>>(xn, wgT, wuT, qkv);
  k_gemm_down<<<dim3(S_ / 128, D_ / 128), 256, 0, stream>>>(qkv, wdT, x1, x, gate, pos, out);
}

// Round 5
// 632.265 us; speedup vs baseline: 1.2875x; 1.1468x over previous
//
#include <hip/hip_runtime.h>
#include <stdint.h>

#define B_ 4
#define T_ 2048
#define D_ 2048
#define H_ 16
#define HD_ 128
#define I_ 5632
#define K_ 512
#define S_ 2048
#define D3_ (3 * D_)

typedef float f32x4 __attribute__((ext_vector_type(4)));
typedef short s16x8 __attribute__((ext_vector_type(8)));
typedef __bf16 bf16x8 __attribute__((ext_vector_type(8)));

// ---------- mfma wrapper robust to builtin operand type (short8 vs bf16x8) ----------
template <typename V>
__device__ __forceinline__ auto mfma_try(V a, V b, f32x4 c, int)
    -> decltype(__builtin_amdgcn_mfma_f32_16x16x32_bf16(a, b, c, 0, 0, 0)) {
  return __builtin_amdgcn_mfma_f32_16x16x32_bf16(a, b, c, 0, 0, 0);
}
template <typename V>
__device__ __forceinline__ f32x4 mfma_try(V a, V b, f32x4 c, long) {
  return __builtin_amdgcn_mfma_f32_16x16x32_bf16(
      __builtin_bit_cast(bf16x8, a), __builtin_bit_cast(bf16x8, b), c, 0, 0, 0);
}
__device__ __forceinline__ f32x4 mfma_bf16(s16x8 a, s16x8 b, f32x4 c) {
  return mfma_try(a, b, c, 0);
}

__device__ __forceinline__ void gl_lds16(const void* g, void* l) {
  __builtin_amdgcn_global_load_lds((const __attribute__((address_space(1))) void*)g,
                                   (__attribute__((address_space(3))) void*)l, 16, 0, 0);
}

__device__ __forceinline__ unsigned short f2bf(float f) {
  unsigned u = __float_as_uint(f);
  u += 0x7FFFu + ((u >> 16) & 1);
  return (unsigned short)(u >> 16);
}
__device__ __forceinline__ float bf2f(unsigned short s) {
  return __uint_as_float(((unsigned)s) << 16);
}

// ---------- K1: copy hidden -> out, fused with router scores ----------
__global__ __launch_bounds__(256) void k_copy_scores(const float4* __restrict__ hid,
                                                     float4* __restrict__ dst,
                                                     const float4* __restrict__ rw,
                                                     const float* __restrict__ rb,
                                                     float* __restrict__ scores) {
  int row = blockIdx.x, t = threadIdx.x;
  const float4* hr = hid + (size_t)row * (D_ / 4);
  float4* dr = dst + (size_t)row * (D_ / 4);
  float acc = 0.f;
#pragma unroll
  for (int i = 0; i < 2; i++) {
    float4 v = hr[t + i * 256];
    dr[t + i * 256] = v;
    float4 w = rw[t + i * 256];
    acc += v.x * w.x + v.y * w.y + v.z * w.z + v.w * w.w;
  }
#pragma unroll
  for (int d = 32; d; d >>= 1) acc += __shfl_xor(acc, d);
  __shared__ float red[4];
  if ((t & 63) == 0) red[t >> 6] = acc;
  __syncthreads();
  if (t == 0) scores[row] = red[0] + red[1] + red[2] + red[3] + rb[0];
}

// ---------- K3: exact top-k (bitonic, matches jax.lax.top_k tie-break) ----------
__global__ __launch_bounds__(1024) void k_topk(const float* __restrict__ scores,
                                               int* __restrict__ pos) {
  __shared__ unsigned long long keys[T_];
  __shared__ int sidx[K_];
  int b = blockIdx.x, t = threadIdx.x;
  for (int i = t; i < T_; i += 1024) {
    unsigned u = __float_as_uint(scores[b * T_ + i]);
    u = (u & 0x80000000u) ? ~u : (u | 0x80000000u);
    keys[i] = ((unsigned long long)u << 32) | (unsigned)(~(unsigned)i);
  }
  __syncthreads();
  for (int k = 2; k <= T_; k <<= 1)
    for (int j = k >> 1; j > 0; j >>= 1) {
      for (int i = t; i < T_; i += 1024) {
        int l = i ^ j;
        if (l > i) {
          unsigned long long a = keys[i], c = keys[l];
          bool desc = ((i & k) == 0);
          if (desc ? (a < c) : (a > c)) { keys[i] = c; keys[l] = a; }
        }
      }
      __syncthreads();
    }
  if (t < K_) sidx[t] = (int)(~(unsigned)(keys[t] & 0xFFFFFFFFull));
  __syncthreads();
  for (int k = 2; k <= K_; k <<= 1)
    for (int j = k >> 1; j > 0; j >>= 1) {
      if (t < K_) {
        int i = t, l = i ^ j;
        if (l > i && l < K_) {
          int a = sidx[i], c = sidx[l];
          bool asc = ((i & k) == 0);
          if (asc ? (a > c) : (a < c)) { sidx[i] = c; sidx[l] = a; }
        }
      }
      __syncthreads();
    }
  if (t < K_) pos[b * K_ + t] = sidx[t];
}

// ---------- K4: gather + RMS1 + gate + rope tables ----------
__global__ __launch_bounds__(256) void k_gather(const float* __restrict__ hidden,
    const int* __restrict__ pos, const float* __restrict__ scores,
    const float* __restrict__ ln1w, float* __restrict__ x,
    unsigned short* __restrict__ xn, float* __restrict__ gate,
    float* __restrict__ cosb, float* __restrict__ sinb) {
  int s = blockIdx.x, t = threadIdx.x;
  int b = s >> 9, p = pos[s];
  const float* src = hidden + ((size_t)b * T_ + p) * D_;
  float v[8];
  float ss = 0.f;
#pragma unroll
  for (int i = 0; i < 8; i++) { v[i] = src[t + i * 256]; ss += v[i] * v[i]; }
  __shared__ float red[4];
#pragma unroll
  for (int d = 32; d; d >>= 1) ss += __shfl_xor(ss, d);
  if ((t & 63) == 0) red[t >> 6] = ss;
  __syncthreads();
  ss = red[0] + red[1] + red[2] + red[3];
  float scale = rsqrtf(ss / (float)D_ + 1e-6f);
  float* xd = x + (size_t)s * D_;
  unsigned short* xnd = xn + (size_t)s * D_;
#pragma unroll
  for (int i = 0; i < 8; i++) {
    int c = t + i * 256;
    xd[c] = v[i];
    xnd[c] = f2bf(v[i] * scale * ln1w[c]);
  }
  if (t == 0) gate[s] = 1.f / (1.f + expf(-scores[b * T_ + p]));
  if (t < 64) {
    float invf = powf(10000.0f, -(float)t / 64.0f);
    float f = (float)p * invf;
    cosb[s * 64 + t] = cosf(f);
    sinb[s * 64 + t] = sinf(f);
  }
}

// ---------- K5: transpose + f32->bf16 (weights to Bt layout) ----------
__global__ __launch_bounds__(256) void k_transpose(const float* __restrict__ src,
                                                   unsigned short* __restrict__ dst,
                                                   int R, int C) {
  __shared__ float tile[32][33];
  int tx = threadIdx.x & 31, ty = threadIdx.x >> 5;
  int c0 = blockIdx.x * 32, r0 = blockIdx.y * 32;
#pragma unroll
  for (int i = 0; i < 4; i++) {
    int r = ty + i * 8;
    tile[r][tx] = src[(size_t)(r0 + r) * C + c0 + tx];
  }
  __syncthreads();
#pragma unroll
  for (int i = 0; i < 4; i++) {
    int r = ty + i * 8;
    dst[(size_t)(c0 + r) * R + r0 + tx] = f2bf(tile[tx][r]);
  }
}

// ======================================================================
// 8-wave 256-wide GEMM template (BK=32, dbuf, counted vmcnt, T2 swizzle)
// ======================================================================
__device__ __forceinline__ void stage16k(const unsigned short* __restrict__ g, int ldK,
                                         int row0, int k0, char* lds, int tid) {
#pragma unroll
  for (int c = 0; c < 2; c++) {
    int off = c * 8192 + tid * 16;
    int row = off >> 6;
    int cb = (off & 63) ^ ((row & 3) << 4);
    gl_lds16(g + (size_t)(row0 + row) * ldK + k0 + (cb >> 1), lds + off);
  }
}
__device__ __forceinline__ void stage8k(const unsigned short* __restrict__ g, int ldK,
                                        int row0, int k0, char* lds, int tid) {
  int off = tid * 16;
  int row = off >> 6;
  int cb = (off & 63) ^ ((row & 3) << 4);
  gl_lds16(g + (size_t)(row0 + row) * ldK + k0 + (cb >> 1), lds + off);
}
__device__ __forceinline__ s16x8 ldfrag(const char* base, int row, int g) {
  return *(const s16x8*)(base + row * 64 + ((g * 16) ^ ((row & 3) << 4)));
}

// ---------- K6: fused QKV GEMM, 256x256 tile, 8 waves, bias epilogue ----------
__global__ __launch_bounds__(512, 2) void k_gemm_qkv8(const unsigned short* __restrict__ A,
    const unsigned short* __restrict__ Bt, unsigned short* __restrict__ C,
    const float* __restrict__ bq, const float* __restrict__ bk,
    const float* __restrict__ bv) {
  alignas(16) __shared__ short As[2][256 * 32];
  alignas(16) __shared__ short Bs[2][256 * 32];
  int tid = threadIdx.x;
  int lane = tid & 63, g = lane >> 4, lr = lane & 15;
  int wid = tid >> 6, wm = wid >> 2, wn = wid & 3;
  int m0 = blockIdx.x * 256, n0 = blockIdx.y * 256;
  f32x4 zero4 = {0.f, 0.f, 0.f, 0.f};
  f32x4 acc[8][4];
#pragma unroll
  for (int m = 0; m < 8; m++)
#pragma unroll
    for (int n = 0; n < 4; n++) acc[m][n] = zero4;
  const int nkt = D_ / 32;
  stage16k(A, D_, m0, 0, (char*)As[0], tid);
  stage16k(Bt, D_, n0, 0, (char*)Bs[0], tid);
  stage16k(A, D_, m0, 32, (char*)As[1], tid);
  stage16k(Bt, D_, n0, 32, (char*)Bs[1], tid);
  int arow = wm * 128 + lr;
  int brow = wn * 64 + lr;
  for (int t = 0; t < nkt; t++) {
    int b = t & 1;
    const char* Ab = (const char*)As[b];
    const char* Bb = (const char*)Bs[b];
    if (t + 1 < nkt) asm volatile("s_waitcnt vmcnt(4)" ::: "memory");
    else             asm volatile("s_waitcnt vmcnt(0)" ::: "memory");
    __builtin_amdgcn_s_barrier();
    s16x8 af[8], bf4[4];
#pragma unroll
    for (int i = 0; i < 4; i++) af[i] = ldfrag(Ab, arow + i * 16, g);
#pragma unroll
    for (int i = 0; i < 4; i++) af[i + 4] = ldfrag(Ab, arow + 64 + i * 16, g);
#pragma unroll
    for (int i = 0; i < 4; i++) bf4[i] = ldfrag(Bb, brow + i * 16, g);
    asm volatile("s_waitcnt lgkmcnt(0)" ::: "memory");
    __builtin_amdgcn_s_barrier();
    if (t + 2 < nkt) {
      stage16k(A, D_, m0, (t + 2) * 32, (char*)As[b], tid);
      stage16k(Bt, D_, n0, (t + 2) * 32, (char*)Bs[b], tid);
    }
    __builtin_amdgcn_s_setprio(1);
#pragma unroll
    for (int m = 0; m < 8; m++)
#pragma unroll
      for (int n = 0; n < 4; n++) acc[m][n] = mfma_bf16(af[m], bf4[n], acc[m][n]);
    __builtin_amdgcn_s_setprio(0);
  }
#pragma unroll
  for (int m = 0; m < 8; m++)
#pragma unroll
    for (int n = 0; n < 4; n++)
#pragma unroll
      for (int r = 0; r < 4; r++) {
        int row = m0 + wm * 128 + m * 16 + (g << 2) + r;
        int col = n0 + wn * 64 + n * 16 + lr;
        float bias = (col < D_) ? bq[col] : ((col < 2 * D_) ? bk[col - D_] : bv[col - 2 * D_]);
        C[(size_t)row * D3_ + col] = f2bf(acc[m][n][r] + bias);
      }
}

// ---------- K11: fused gate/up GEMM, 256x(128+128) tile, 8 waves, silu*mul ----------
__global__ __launch_bounds__(512, 2) void k_gemm_gup8(const unsigned short* __restrict__ A,
    const unsigned short* __restrict__ Bg, const unsigned short* __restrict__ Bu,
    unsigned short* __restrict__ act) {
  alignas(16) __shared__ short As[2][256 * 32];
  alignas(16) __shared__ short Bgs[2][128 * 32];
  alignas(16) __shared__ short Bus[2][128 * 32];
  int tid = threadIdx.x;
  int lane = tid & 63, g = lane >> 4, lr = lane & 15;
  int wid = tid >> 6, wm = wid >> 1, wn = wid & 1;
  int m0 = blockIdx.x * 256, n0 = blockIdx.y * 128;
  f32x4 zero4 = {0.f, 0.f, 0.f, 0.f};
  f32x4 ag[4][4], au[4][4];
#pragma unroll
  for (int m = 0; m < 4; m++)
#pragma unroll
    for (int n = 0; n < 4; n++) { ag[m][n] = zero4; au[m][n] = zero4; }
  const int nkt = D_ / 32;
  stage16k(A, D_, m0, 0, (char*)As[0], tid);
  stage8k(Bg, D_, n0, 0, (char*)Bgs[0], tid);
  stage8k(Bu, D_, n0, 0, (char*)Bus[0], tid);
  stage16k(A, D_, m0, 32, (char*)As[1], tid);
  stage8k(Bg, D_, n0, 32, (char*)Bgs[1], tid);
  stage8k(Bu, D_, n0, 32, (char*)Bus[1], tid);
  int arow = wm * 64 + lr;
  int brow = wn * 64 + lr;
  for (int t = 0; t < nkt; t++) {
    int b = t & 1;
    const char* Ab = (const char*)As[b];
    const char* Bgb = (const char*)Bgs[b];
    const char* Bub = (const char*)Bus[b];
    if (t + 1 < nkt) asm volatile("s_waitcnt vmcnt(4)" ::: "memory");
    else             asm volatile("s_waitcnt vmcnt(0)" ::: "memory");
    __builtin_amdgcn_s_barrier();
    s16x8 af[4], bg4[4], bu4[4];
#pragma unroll
    for (int i = 0; i < 4; i++) af[i] = ldfrag(Ab, arow + i * 16, g);
#pragma unroll
    for (int i = 0; i < 4; i++) bg4[i] = ldfrag(Bgb, brow + i * 16, g);
#pragma unroll
    for (int i = 0; i < 4; i++) bu4[i] = ldfrag(Bub, brow + i * 16, g);
    asm volatile("s_waitcnt lgkmcnt(0)" ::: "memory");
    __builtin_amdgcn_s_barrier();
    if (t + 2 < nkt) {
      stage16k(A, D_, m0, (t + 2) * 32, (char*)As[b], tid);
      stage8k(Bg, D_, n0, (t + 2) * 32, (char*)Bgs[b], tid);
      stage8k(Bu, D_, n0, (t + 2) * 32, (char*)Bus[b], tid);
    }
    __builtin_amdgcn_s_setprio(1);
#pragma unroll
    for (int m = 0; m < 4; m++)
#pragma unroll
      for (int n = 0; n < 4; n++) {
        ag[m][n] = mfma_bf16(af[m], bg4[n], ag[m][n]);
        au[m][n] = mfma_bf16(af[m], bu4[n], au[m][n]);
      }
    __builtin_amdgcn_s_setprio(0);
  }
#pragma unroll
  for (int m = 0; m < 4; m++)
#pragma unroll
    for (int n = 0; n < 4; n++)
#pragma unroll
      for (int r = 0; r < 4; r++) {
        int row = m0 + wm * 64 + m * 16 + (g << 2) + r;
        int col = n0 + wn * 64 + n * 16 + lr;
        float gv = ag[m][n][r], uv = au[m][n][r];
        float si = gv / (1.f + __expf(-gv));
        act[(size_t)row * I_ + col] = f2bf(si * uv);
      }
}

// ---------- GEMM building blocks (128x128 tile, BK=32, dbuf 2-phase) ----------
__device__ __forceinline__ void stage_tile(const unsigned short* __restrict__ gbase,
                                           int ldK, int row0, int k0, char* lds, int tid) {
  int w = tid >> 6, lane = tid & 63;
#pragma unroll
  for (int p = 0; p < 2; p++) {
    int ldsoff = p * 4096 + w * 1024;
    int boff = ldsoff + lane * 16;
    int row = boff >> 6;
    int ke = (boff & 63) >> 1;
    gl_lds16(gbase + (size_t)(row0 + row) * ldK + k0 + ke, lds + ldsoff);
  }
}

__device__ __forceinline__ void gemm_step(const char* As, const char* Bs, int wr, int wc,
                                          int g, int lr, f32x4 acc[4][4]) {
  s16x8 af[4], bf4[4];
#pragma unroll
  for (int i = 0; i < 4; i++)
    af[i] = *(const s16x8*)(As + ((wr + i * 16 + lr) << 6) + (g << 4));
#pragma unroll
  for (int i = 0; i < 4; i++)
    bf4[i] = *(const s16x8*)(Bs + ((wc + i * 16 + lr) << 6) + (g << 4));
#pragma unroll
  for (int m = 0; m < 4; m++)
#pragma unroll
    for (int n = 0; n < 4; n++) acc[m][n] = mfma_bf16(af[m], bf4[n], acc[m][n]);
}

#define GEMM_PRE()                                                     \
  int tid = threadIdx.x;                                               \
  int w = tid >> 6, lane = tid & 63, g = lane >> 4, lr = lane & 15;    \
  int wr = (w >> 1) * 64, wc = (w & 1) * 64;                           \
  int m0 = blockIdx.x * 128, n0 = blockIdx.y * 128;                    \
  f32x4 zero4 = {0.f, 0.f, 0.f, 0.f};                                  \
  (void)lane;

// ---------- K7: RoPE + head relayout (q,k row-major per head; v transposed) ----------
__global__ __launch_bounds__(256) void k_rope(const unsigned short* __restrict__ qkv,
    const float* __restrict__ cosb, const float* __restrict__ sinb,
    unsigned short* __restrict__ qh, unsigned short* __restrict__ kh,
    unsigned short* __restrict__ vT) {
  int s0 = blockIdx.x * 64;
  int h = blockIdx.y;
  int t = threadIdx.x;
#pragma unroll
  for (int i = 0; i < 16; i++) {
    int flat = t + i * 256;
    int r = flat >> 6, dp = flat & 63;
    int s = s0 + r;
    float c = cosb[s * 64 + dp], sn = sinb[s * 64 + dp];
    const unsigned short* qrow = qkv + (size_t)s * D3_ + h * HD_;
    float q1 = bf2f(qrow[dp]), q2 = bf2f(qrow[dp + 64]);
    unsigned short* qdst = qh + ((size_t)h * S_ + s) * HD_;
    qdst[dp] = f2bf(q1 * c - q2 * sn);
    qdst[dp + 64] = f2bf(q2 * c + q1 * sn);
    const unsigned short* krow = qrow + D_;
    float k1 = bf2f(krow[dp]), k2 = bf2f(krow[dp + 64]);
    unsigned short* kdst = kh + ((size_t)h * S_ + s) * HD_;
    kdst[dp] = f2bf(k1 * c - k2 * sn);
    kdst[dp + 64] = f2bf(k2 * c + k1 * sn);
  }
  __shared__ unsigned short vt[128][66];
#pragma unroll
  for (int i = 0; i < 32; i++) {
    int flat = t + i * 256;
    int r = flat >> 7, d = flat & 127;
    vt[d][r] = qkv[(size_t)(s0 + r) * D3_ + 2 * D_ + h * HD_ + d];
  }
  __syncthreads();
#pragma unroll
  for (int i = 0; i < 32; i++) {
    int flat = t + i * 256;
    int d = flat >> 6, sc = flat & 63;
    vT[((size_t)h * HD_ + d) * S_ + s0 + sc] = vt[d][sc];
  }
}

// ======================================================================
// K8: flash attention, rebuilt:
//  - q-tile 64 (4 waves x 16 rows) -> grid 32x16 = 512 blocks, 2 blocks/CU
//  - LPT: heavy q-tiles dispatch first (qt = slot<16 ? 31-slot : slot-16)
//  - Ks/Vs/Ps XOR-swizzled byte^=((row&7)<<4), both-sides (G4 recipe)
//  - K/V double-buffered, counted vmcnt(8), raw barriers (R4 GEMM pattern)
// ======================================================================
__device__ __forceinline__ void stage_kv(const unsigned short* __restrict__ kh,
                                         const unsigned short* __restrict__ vT,
                                         size_t hbase, int kt, char* KsB, char* VsB, int tid) {
#pragma unroll
  for (int c = 0; c < 4; c++) {
    int off = c * 4096 + tid * 16;
    int row = off >> 8;
    int cb = (off & 255) ^ ((row & 7) << 4);
    gl_lds16(kh + hbase + (size_t)(kt * 64 + row) * HD_ + (cb >> 1), KsB + off);
  }
#pragma unroll
  for (int c = 0; c < 4; c++) {
    int off = c * 4096 + tid * 16;
    int row = off >> 7;
    int cb = (off & 127) ^ ((row & 7) << 4);
    gl_lds16(vT + hbase + (size_t)row * S_ + kt * 64 + (cb >> 1), VsB + off);
  }
}

__global__ __launch_bounds__(256, 2) void k_attn(const unsigned short* __restrict__ qh,
                                                 const unsigned short* __restrict__ kh,
                                                 const unsigned short* __restrict__ vT,
                                                 unsigned short* __restrict__ ao) {
  alignas(16) __shared__ short Ks[2][64 * 128];   // [kv][d], 256B rows, swizzled
  alignas(16) __shared__ short Vs[2][128 * 64];   // [d][kv], 128B rows, swizzled
  alignas(16) __shared__ short Ps[4][16 * 64];    // per-wave P, 128B rows, swizzled
  int bidx = blockIdx.x;
  int head = bidx & 15;
  int slot = bidx >> 4;                      // 0..31
  int qt = (slot < 16) ? (31 - slot) : (slot - 16);
  int q0 = qt * 64;
  int tid = threadIdx.x, w = tid >> 6, lane = tid & 63, g = lane >> 4, lr = lane & 15;
  size_t hbase = (size_t)head * S_ * HD_;
  int qw = q0 + w * 16;
  char* PsW = (char*)&Ps[w][0];
  // Q fragments (16 rows per wave), from global
  s16x8 qf[4];
#pragma unroll
  for (int ks = 0; ks < 4; ks++)
    qf[ks] = *(const s16x8*)&qh[hbase + (size_t)(qw + lr) * HD_ + ks * 32 + g * 8];
  f32x4 o[8];
  f32x4 zero4 = {0.f, 0.f, 0.f, 0.f};
#pragma unroll
  for (int nf = 0; nf < 8; nf++) o[nf] = zero4;
  float m_i[4], l_i[4];
#pragma unroll
  for (int r = 0; r < 4; r++) { m_i[r] = -1e30f; l_i[r] = 0.f; }
  const float sc = 0.08838834764831843f;  // 1/sqrt(128)

  stage_kv(kh, vT, hbase, 0, (char*)Ks[0], (char*)Vs[0], tid);
  if (qt > 0) stage_kv(kh, vT, hbase, 1, (char*)Ks[1], (char*)Vs[1], tid);

  for (int kt = 0; kt <= qt; kt++) {
    int b = kt & 1;
    const char* KsB = (const char*)Ks[b];
    const char* VsB = (const char*)Vs[b];
    if (kt < qt) asm volatile("s_waitcnt vmcnt(8)" ::: "memory");
    else         asm volatile("s_waitcnt vmcnt(0)" ::: "memory");
    __builtin_amdgcn_s_barrier();
    // ---- QK^T: S[16 q][64 kv] ----
    f32x4 sacc[4];
#pragma unroll
    for (int nf = 0; nf < 4; nf++) sacc[nf] = zero4;
#pragma unroll
    for (int ks = 0; ks < 4; ks++) {
      s16x8 kf[4];
#pragma unroll
      for (int nf = 0; nf < 4; nf++) {
        int row = nf * 16 + lr;
        kf[nf] = *(const s16x8*)(KsB + row * 256 + (((ks << 6) + (g << 4)) ^ ((row & 7) << 4)));
      }
#pragma unroll
      for (int nf = 0; nf < 4; nf++) sacc[nf] = mfma_bf16(qf[ks], kf[nf], sacc[nf]);
    }
    // ---- online softmax (rows r = (g<<2)+r of this wave's 16) ----
    bool diag = (kt == qt);
#pragma unroll
    for (int r = 0; r < 4; r++) {
      int prow = (g << 2) + r;
      int qrow = qw + prow;
      float pv[4];
      float mx = -1e30f;
#pragma unroll
      for (int nf = 0; nf < 4; nf++) {
        float vv = sacc[nf][r] * sc;
        if (diag) {
          int kc = kt * 64 + nf * 16 + lr;
          vv = (kc <= qrow) ? vv : -1e30f;
        }
        pv[nf] = vv;
        mx = fmaxf(mx, vv);
      }
#pragma unroll
      for (int d = 1; d < 16; d <<= 1) mx = fmaxf(mx, __shfl_xor(mx, d));
      float mold = m_i[r], mnew = fmaxf(mold, mx);
      float corr = __expf(mold - mnew);
      float ssum = 0.f;
#pragma unroll
      for (int nf = 0; nf < 4; nf++) {
        float pe = __expf(pv[nf] - mnew);
        int cb = ((nf * 16 + lr) << 1) ^ ((prow & 7) << 4);
        *(unsigned short*)(PsW + prow * 128 + cb) = f2bf(pe);
        ssum += pe;
      }
#pragma unroll
      for (int d = 1; d < 16; d <<= 1) ssum += __shfl_xor(ssum, d);
      l_i[r] = l_i[r] * corr + ssum;
      m_i[r] = mnew;
#pragma unroll
      for (int nf = 0; nf < 8; nf++) o[nf][r] *= corr;
    }
    // ---- PV: O[16 q][128 d] += P[16][64] x V[64][128] ----
    s16x8 pa[2];
#pragma unroll
    for (int ks = 0; ks < 2; ks++)
      pa[ks] = *(const s16x8*)(PsW + lr * 128 + (((ks << 6) + (g << 4)) ^ ((lr & 7) << 4)));
#pragma unroll
    for (int nf = 0; nf < 8; nf++) {
#pragma unroll
      for (int ks = 0; ks < 2; ks++) {
        int row = nf * 16 + lr;
        s16x8 vb = *(const s16x8*)(VsB + row * 128 + (((ks << 6) + (g << 4)) ^ ((row & 7) << 4)));
        o[nf] = mfma_bf16(pa[ks], vb, o[nf]);
      }
    }
    asm volatile("s_waitcnt lgkmcnt(0)" ::: "memory");
    __builtin_amdgcn_s_barrier();
    if (kt + 2 <= qt)
      stage_kv(kh, vT, hbase, kt + 2, (char*)Ks[b], (char*)Vs[b], tid);
  }
#pragma unroll
  for (int nf = 0; nf < 8; nf++)
#pragma unroll
    for (int r = 0; r < 4; r++) {
      int row = qw + (g << 2) + r;
      int col = head * HD_ + nf * 16 + lr;
      ao[(size_t)row * D_ + col] = f2bf(o[nf][r] / l_i[r]);
    }
}

// ---------- K9: wo GEMM + residual ----------
__global__ __launch_bounds__(256) void k_gemm_wo(const unsigned short* __restrict__ A,
    const unsigned short* __restrict__ Bt, const float* __restrict__ xres,
    float* __restrict__ x1) {
  alignas(16) __shared__ short As[2][128 * 32];
  alignas(16) __shared__ short Bs[2][128 * 32];
  GEMM_PRE();
  f32x4 acc[4][4];
#pragma unroll
  for (int m = 0; m < 4; m++)
#pragma unroll
    for (int n = 0; n < 4; n++) acc[m][n] = zero4;
  stage_tile(A, D_, m0, 0, (char*)As[0], tid);
  stage_tile(Bt, D_, n0, 0, (char*)Bs[0], tid);
  __syncthreads();
  int cur = 0;
  for (int k0 = 0; k0 < D_; k0 += 32) {
    if (k0 + 32 < D_) {
      stage_tile(A, D_, m0, k0 + 32, (char*)As[cur ^ 1], tid);
      stage_tile(Bt, D_, n0, k0 + 32, (char*)Bs[cur ^ 1], tid);
    }
    gemm_step((const char*)As[cur], (const char*)Bs[cur], wr, wc, g, lr, acc);
    __syncthreads();
    cur ^= 1;
  }
#pragma unroll
  for (int m = 0; m < 4; m++)
#pragma unroll
    for (int n = 0; n < 4; n++)
#pragma unroll
      for (int r = 0; r < 4; r++) {
        int row = m0 + wr + m * 16 + (g << 2) + r;
        int col = n0 + wc + n * 16 + lr;
        x1[(size_t)row * D_ + col] = acc[m][n][r] + xres[(size_t)row * D_ + col];
      }
}

// ---------- K10: RMS2 ----------
__global__ __launch_bounds__(256) void k_rms2(const float* __restrict__ x1,
                                              const float* __restrict__ ln2w,
                                              unsigned short* __restrict__ xn2) {
  int s = blockIdx.x, t = threadIdx.x;
  const float* src = x1 + (size_t)s * D_;
  float v[8];
  float ss = 0.f;
#pragma unroll
  for (int i = 0; i < 8; i++) { v[i] = src[t + i * 256]; ss += v[i] * v[i]; }
  __shared__ float red[4];
#pragma unroll
  for (int d = 32; d; d >>= 1) ss += __shfl_xor(ss, d);
  if ((t & 63) == 0) red[t >> 6] = ss;
  __syncthreads();
  ss = red[0] + red[1] + red[2] + red[3];
  float scale = rsqrtf(ss / (float)D_ + 1e-6f);
  unsigned short* dst = xn2 + (size_t)s * D_;
#pragma unroll
  for (int i = 0; i < 8; i++) {
    int c = t + i * 256;
    dst[c] = f2bf(v[i] * scale * ln2w[c]);
  }
}

// ---------- K12: down GEMM + residual + sigmoid blend + scatter ----------
__global__ __launch_bounds__(256) void k_gemm_down(const unsigned short* __restrict__ A,
    const unsigned short* __restrict__ Bt, const float* __restrict__ x1,
    const float* __restrict__ x, const float* __restrict__ gate,
    const int* __restrict__ pos, float* __restrict__ out) {
  alignas(16) __shared__ short As[2][128 * 32];
  alignas(16) __shared__ short Bs[2][128 * 32];
  GEMM_PRE();
  f32x4 acc[4][4];
#pragma unroll
  for (int m = 0; m < 4; m++)
#pragma unroll
    for (int n = 0; n < 4; n++) acc[m][n] = zero4;
  stage_tile(A, I_, m0, 0, (char*)As[0], tid);
  stage_tile(Bt, I_, n0, 0, (char*)Bs[0], tid);
  __syncthreads();
  int cur = 0;
  for (int k0 = 0; k0 < I_; k0 += 32) {
    if (k0 + 32 < I_) {
      stage_tile(A, I_, m0, k0 + 32, (char*)As[cur ^ 1], tid);
      stage_tile(Bt, I_, n0, k0 + 32, (char*)Bs[cur ^ 1], tid);
    }
    gemm_step((const char*)As[cur], (const char*)Bs[cur], wr, wc, g, lr, acc);
    __syncthreads();
    cur ^= 1;
  }
#pragma unroll
  for (int m = 0; m < 4; m++)
#pragma unroll
    for (int n = 0; n < 4; n++)
#pragma unroll
      for (int r = 0; r < 4; r++) {
        int srow = m0 + wr + m * 16 + (g << 2) + r;
        int col = n0 + wc + n * 16 + lr;
        float proc = acc[m][n][r] + x1[(size_t)srow * D_ + col];
        float gt = gate[srow];
        float xv = x[(size_t)srow * D_ + col];
        int bb = srow >> 9;
        int p = pos[srow];
        out[((size_t)bb * T_ + p) * D_ + col] = gt * proc + (1.f - gt) * xv;
      }
}

extern "C" void kernel_launch(void* const* d_in, const int* in_sizes, int n_in,
                              void* d_out, int out_size, void* d_ws, size_t ws_size,
                              hipStream_t stream) {
  (void)in_sizes; (void)n_in; (void)out_size; (void)ws_size;
  const float* hidden = (const float*)d_in[0];
  const float* router_w = (const float*)d_in[1];
  const float* router_b = (const float*)d_in[2];
  const float* ln1w = (const float*)d_in[3];
  const float* ln2w = (const float*)d_in[4];
  const float* wq = (const float*)d_in[5];
  const float* bq = (const float*)d_in[6];
  const float* wk = (const float*)d_in[7];
  const float* bk = (const float*)d_in[8];
  const float* wv = (const float*)d_in[9];
  const float* bv = (const float*)d_in[10];
  const float* wo = (const float*)d_in[11];
  const float* wg = (const float*)d_in[12];
  const float* wu = (const float*)d_in[13];
  const float* wd = (const float*)d_in[14];
  float* out = (float*)d_out;

  char* ws = (char*)d_ws;
  size_t off = 0;
  auto alloc = [&](size_t bytes) {
    char* p = ws + off;
    off += (bytes + 255) & ~(size_t)255;
    return p;
  };
  unsigned short* wqkvT = (unsigned short*)alloc(3ull * D_ * D_ * 2);
  unsigned short* woT = (unsigned short*)alloc((size_t)D_ * D_ * 2);
  unsigned short* wgT = (unsigned short*)alloc((size_t)I_ * D_ * 2);
  unsigned short* wuT = (unsigned short*)alloc((size_t)I_ * D_ * 2);
  unsigned short* wdT = (unsigned short*)alloc((size_t)D_ * I_ * 2);
  float* scores = (float*)alloc((size_t)B_ * T_ * 4);
  int* pos = (int*)alloc((size_t)S_ * 4);
  float* gate = (float*)alloc((size_t)S_ * 4);
  float* x = (float*)alloc((size_t)S_ * D_ * 4);
  float* x1 = (float*)alloc((size_t)S_ * D_ * 4);
  unsigned short* xn = (unsigned short*)alloc((size_t)S_ * D_ * 2);  // reused as x1n
  float* cosb = (float*)alloc((size_t)S_ * 64 * 4);
  float* sinb = (float*)alloc((size_t)S_ * 64 * 4);
  unsigned short* qkv = (unsigned short*)alloc((size_t)S_ * D3_ * 2);  // reused as act
  unsigned short* qh = (unsigned short*)alloc((size_t)H_ * S_ * HD_ * 2);
  unsigned short* kh = (unsigned short*)alloc((size_t)H_ * S_ * HD_ * 2);
  unsigned short* vT = (unsigned short*)alloc((size_t)H_ * S_ * HD_ * 2);
  unsigned short* ao = (unsigned short*)alloc((size_t)S_ * D_ * 2);

  k_copy_scores<<<B_ * T_, 256, 0, stream>>>((const float4*)hidden, (float4*)out,
                                             (const float4*)router_w, router_b, scores);

  k_transpose<<<dim3(D_ / 32, D_ / 32), 256, 0, stream>>>(wq, wqkvT, D_, D_);
  k_transpose<<<dim3(D_ / 32, D_ / 32), 256, 0, stream>>>(wk, wqkvT + (size_t)D_ * D_, D_, D_);
  k_transpose<<<dim3(D_ / 32, D_ / 32), 256, 0, stream>>>(wv, wqkvT + 2ull * D_ * D_, D_, D_);
  k_transpose<<<dim3(D_ / 32, D_ / 32), 256, 0, stream>>>(wo, woT, D_, D_);
  k_transpose<<<dim3(I_ / 32, D_ / 32), 256, 0, stream>>>(wg, wgT, D_, I_);
  k_transpose<<<dim3(I_ / 32, D_ / 32), 256, 0, stream>>>(wu, wuT, D_, I_);
  k_transpose<<<dim3(D_ / 32, I_ / 32), 256, 0, stream>>>(wd, wdT, I_, D_);

  k_topk<<<B_, 1024, 0, stream>>>(scores, pos);
  k_gather<<<S_, 256, 0, stream>>>(hidden, pos, scores, ln1w, x, xn, gate, cosb, sinb);

  k_gemm_qkv8<<<dim3(S_ / 256, D3_ / 256), 512, 0, stream>>>(xn, wqkvT, qkv, bq, bk, bv);
  k_rope<<<dim3(S_ / 64, H_), 256, 0, stream>>>(qkv, cosb, sinb, qh, kh, vT);
  k_attn<<<32 * H_, 256, 0, stream>>>(qh, kh, vT, ao);
  k_gemm_wo<<<dim3(S_ / 128, D_ / 128), 256, 0, stream>>>(ao, woT, x, x1);
  k_rms2<<<S_, 256, 0, stream>>>(x1, ln2w, xn);
  k_gemm_gup8<<<dim3(S_ / 256, I_ / 128), 512, 0, stream>>>(xn, wgT, wuT, qkv);
  k_gemm_down<<<dim3(S_ / 128, D_ / 128), 256, 0, stream>>>(qkv, wdT, x1, x, gate, pos, out);
}

// Round 6
// 566.884 us; speedup vs baseline: 1.4360x; 1.1153x over previous
//
#include <hip/hip_runtime.h>
#include <stdint.h>

#define B_ 4
#define T_ 2048
#define D_ 2048
#define H_ 16
#define HD_ 128
#define I_ 5632
#define K_ 512
#define S_ 2048
#define D3_ (3 * D_)

typedef float f32x4 __attribute__((ext_vector_type(4)));
typedef short s16x8 __attribute__((ext_vector_type(8)));
typedef __bf16 bf16x8 __attribute__((ext_vector_type(8)));

// ---------- mfma wrapper robust to builtin operand type (short8 vs bf16x8) ----------
template <typename V>
__device__ __forceinline__ auto mfma_try(V a, V b, f32x4 c, int)
    -> decltype(__builtin_amdgcn_mfma_f32_16x16x32_bf16(a, b, c, 0, 0, 0)) {
  return __builtin_amdgcn_mfma_f32_16x16x32_bf16(a, b, c, 0, 0, 0);
}
template <typename V>
__device__ __forceinline__ f32x4 mfma_try(V a, V b, f32x4 c, long) {
  return __builtin_amdgcn_mfma_f32_16x16x32_bf16(
      __builtin_bit_cast(bf16x8, a), __builtin_bit_cast(bf16x8, b), c, 0, 0, 0);
}
__device__ __forceinline__ f32x4 mfma_bf16(s16x8 a, s16x8 b, f32x4 c) {
  return mfma_try(a, b, c, 0);
}

__device__ __forceinline__ void gl_lds16(const void* g, void* l) {
  __builtin_amdgcn_global_load_lds((const __attribute__((address_space(1))) void*)g,
                                   (__attribute__((address_space(3))) void*)l, 16, 0, 0);
}

__device__ __forceinline__ unsigned short f2bf(float f) {
  unsigned u = __float_as_uint(f);
  u += 0x7FFFu + ((u >> 16) & 1);
  return (unsigned short)(u >> 16);
}
__device__ __forceinline__ float bf2f(unsigned short s) {
  return __uint_as_float(((unsigned)s) << 16);
}

// ---------- K1: copy hidden -> out, fused with router scores ----------
__global__ __launch_bounds__(256) void k_copy_scores(const float4* __restrict__ hid,
                                                     float4* __restrict__ dst,
                                                     const float4* __restrict__ rw,
                                                     const float* __restrict__ rb,
                                                     float* __restrict__ scores) {
  int row = blockIdx.x, t = threadIdx.x;
  const float4* hr = hid + (size_t)row * (D_ / 4);
  float4* dr = dst + (size_t)row * (D_ / 4);
  float acc = 0.f;
#pragma unroll
  for (int i = 0; i < 2; i++) {
    float4 v = hr[t + i * 256];
    dr[t + i * 256] = v;
    float4 w = rw[t + i * 256];
    acc += v.x * w.x + v.y * w.y + v.z * w.z + v.w * w.w;
  }
#pragma unroll
  for (int d = 32; d; d >>= 1) acc += __shfl_xor(acc, d);
  __shared__ float red[4];
  if ((t & 63) == 0) red[t >> 6] = acc;
  __syncthreads();
  if (t == 0) scores[row] = red[0] + red[1] + red[2] + red[3] + rb[0];
}

// ---------- K3: exact top-k (bitonic, matches jax.lax.top_k tie-break) ----------
__global__ __launch_bounds__(1024) void k_topk(const float* __restrict__ scores,
                                               int* __restrict__ pos) {
  __shared__ unsigned long long keys[T_];
  __shared__ int sidx[K_];
  int b = blockIdx.x, t = threadIdx.x;
  for (int i = t; i < T_; i += 1024) {
    unsigned u = __float_as_uint(scores[b * T_ + i]);
    u = (u & 0x80000000u) ? ~u : (u | 0x80000000u);
    keys[i] = ((unsigned long long)u << 32) | (unsigned)(~(unsigned)i);
  }
  __syncthreads();
  for (int k = 2; k <= T_; k <<= 1)
    for (int j = k >> 1; j > 0; j >>= 1) {
      for (int i = t; i < T_; i += 1024) {
        int l = i ^ j;
        if (l > i) {
          unsigned long long a = keys[i], c = keys[l];
          bool desc = ((i & k) == 0);
          if (desc ? (a < c) : (a > c)) { keys[i] = c; keys[l] = a; }
        }
      }
      __syncthreads();
    }
  if (t < K_) sidx[t] = (int)(~(unsigned)(keys[t] & 0xFFFFFFFFull));
  __syncthreads();
  for (int k = 2; k <= K_; k <<= 1)
    for (int j = k >> 1; j > 0; j >>= 1) {
      if (t < K_) {
        int i = t, l = i ^ j;
        if (l > i && l < K_) {
          int a = sidx[i], c = sidx[l];
          bool asc = ((i & k) == 0);
          if (asc ? (a > c) : (a < c)) { sidx[i] = c; sidx[l] = a; }
        }
      }
      __syncthreads();
    }
  if (t < K_) pos[b * K_ + t] = sidx[t];
}

// ---------- K4: gather + RMS1 + gate + rope tables ----------
__global__ __launch_bounds__(256) void k_gather(const float* __restrict__ hidden,
    const int* __restrict__ pos, const float* __restrict__ scores,
    const float* __restrict__ ln1w, float* __restrict__ x,
    unsigned short* __restrict__ xn, float* __restrict__ gate,
    float* __restrict__ cosb, float* __restrict__ sinb) {
  int s = blockIdx.x, t = threadIdx.x;
  int b = s >> 9, p = pos[s];
  const float* src = hidden + ((size_t)b * T_ + p) * D_;
  float v[8];
  float ss = 0.f;
#pragma unroll
  for (int i = 0; i < 8; i++) { v[i] = src[t + i * 256]; ss += v[i] * v[i]; }
  __shared__ float red[4];
#pragma unroll
  for (int d = 32; d; d >>= 1) ss += __shfl_xor(ss, d);
  if ((t & 63) == 0) red[t >> 6] = ss;
  __syncthreads();
  ss = red[0] + red[1] + red[2] + red[3];
  float scale = rsqrtf(ss / (float)D_ + 1e-6f);
  float* xd = x + (size_t)s * D_;
  unsigned short* xnd = xn + (size_t)s * D_;
#pragma unroll
  for (int i = 0; i < 8; i++) {
    int c = t + i * 256;
    xd[c] = v[i];
    xnd[c] = f2bf(v[i] * scale * ln1w[c]);
  }
  if (t == 0) gate[s] = 1.f / (1.f + expf(-scores[b * T_ + p]));
  if (t < 64) {
    float invf = powf(10000.0f, -(float)t / 64.0f);
    float f = (float)p * invf;
    cosb[s * 64 + t] = cosf(f);
    sinb[s * 64 + t] = sinf(f);
  }
}

// ---------- K5: transpose + f32->bf16 (weights to Bt layout) ----------
__global__ __launch_bounds__(256) void k_transpose(const float* __restrict__ src,
                                                   unsigned short* __restrict__ dst,
                                                   int R, int C) {
  __shared__ float tile[32][33];
  int tx = threadIdx.x & 31, ty = threadIdx.x >> 5;
  int c0 = blockIdx.x * 32, r0 = blockIdx.y * 32;
#pragma unroll
  for (int i = 0; i < 4; i++) {
    int r = ty + i * 8;
    tile[r][tx] = src[(size_t)(r0 + r) * C + c0 + tx];
  }
  __syncthreads();
#pragma unroll
  for (int i = 0; i < 4; i++) {
    int r = ty + i * 8;
    dst[(size_t)(c0 + r) * R + r0 + tx] = f2bf(tile[tx][r]);
  }
}

// ======================================================================
// GEMM template (BK=32, dbuf, counted vmcnt).
// LDS rows are 64 B. Swizzle involution: byte ^= (((row>>1)&3)<<4).
//   bank = 16*(row&1) + 4*(g ^ ((row>>1)&3)) -> 16 lanes cover 8 distinct
//   bank-quads x 2 lanes = 2-way = free (m136). Applied to the GLOBAL
//   source (gl_lds dest must be linear, m104/m173) and to the read.
// Schedule per K-tile t (buffer b = t&1):
//   vmcnt(loads_per_tile) -> barrier -> ds_read all frags -> lgkmcnt(0)
//   -> barrier -> stage tile t+2 into buf b -> setprio(1) MFMA setprio(0)
// ======================================================================
#define SWZ(row) ((((row) >> 1) & 3) << 4)

// 512-thread staging helpers
__device__ __forceinline__ void stage16k(const unsigned short* __restrict__ g, int ldK,
                                         int row0, int k0, char* lds, int tid) {
#pragma unroll
  for (int c = 0; c < 2; c++) {
    int off = c * 8192 + tid * 16;  // 16 KB = 256 rows
    int row = off >> 6;
    int cb = (off & 63) ^ SWZ(row);
    gl_lds16(g + (size_t)(row0 + row) * ldK + k0 + (cb >> 1), lds + off);
  }
}
__device__ __forceinline__ void stage8k(const unsigned short* __restrict__ g, int ldK,
                                        int row0, int k0, char* lds, int tid) {
  int off = tid * 16;  // 8 KB = 128 rows (512 thr)
  int row = off >> 6;
  int cb = (off & 63) ^ SWZ(row);
  gl_lds16(g + (size_t)(row0 + row) * ldK + k0 + (cb >> 1), lds + off);
}
// 256-thread staging helpers
__device__ __forceinline__ void stage64r(const unsigned short* __restrict__ g, int ldK,
                                         int row0, int k0, char* lds, int tid) {
  int off = tid * 16;  // 4 KB = 64 rows (256 thr)
  int row = off >> 6;
  int cb = (off & 63) ^ SWZ(row);
  gl_lds16(g + (size_t)(row0 + row) * ldK + k0 + (cb >> 1), lds + off);
}
__device__ __forceinline__ void stage128r(const unsigned short* __restrict__ g, int ldK,
                                          int row0, int k0, char* lds, int tid) {
#pragma unroll
  for (int c = 0; c < 2; c++) {
    int off = c * 4096 + tid * 16;  // 8 KB = 128 rows (256 thr)
    int row = off >> 6;
    int cb = (off & 63) ^ SWZ(row);
    gl_lds16(g + (size_t)(row0 + row) * ldK + k0 + (cb >> 1), lds + off);
  }
}
__device__ __forceinline__ s16x8 ldfrag(const char* base, int row, int g) {
  return *(const s16x8*)(base + row * 64 + ((g * 16) ^ SWZ(row)));
}

// ---------- K6: fused QKV GEMM, 256x128 tile, 8 waves, bias epilogue ----------
__global__ __launch_bounds__(512, 2) void k_gemm_qkv8(const unsigned short* __restrict__ A,
    const unsigned short* __restrict__ Bt, unsigned short* __restrict__ C,
    const float* __restrict__ bq, const float* __restrict__ bk,
    const float* __restrict__ bv) {
  alignas(16) __shared__ short As[2][256 * 32];
  alignas(16) __shared__ short Bs[2][128 * 32];
  int tid = threadIdx.x;
  int lane = tid & 63, g = lane >> 4, lr = lane & 15;
  int wid = tid >> 6, wm = wid >> 1, wn = wid & 1;
  int m0 = blockIdx.x * 256, n0 = blockIdx.y * 128;
  f32x4 zero4 = {0.f, 0.f, 0.f, 0.f};
  f32x4 acc[4][4];
#pragma unroll
  for (int m = 0; m < 4; m++)
#pragma unroll
    for (int n = 0; n < 4; n++) acc[m][n] = zero4;
  const int nkt = D_ / 32;
  stage16k(A, D_, m0, 0, (char*)As[0], tid);
  stage8k(Bt, D_, n0, 0, (char*)Bs[0], tid);
  stage16k(A, D_, m0, 32, (char*)As[1], tid);
  stage8k(Bt, D_, n0, 32, (char*)Bs[1], tid);
  int arow = wm * 64 + lr;
  int brow = wn * 64 + lr;
  for (int t = 0; t < nkt; t++) {
    int b = t & 1;
    const char* Ab = (const char*)As[b];
    const char* Bb = (const char*)Bs[b];
    if (t + 1 < nkt) asm volatile("s_waitcnt vmcnt(3)" ::: "memory");
    else             asm volatile("s_waitcnt vmcnt(0)" ::: "memory");
    __builtin_amdgcn_s_barrier();
    s16x8 af[4], bf4[4];
#pragma unroll
    for (int i = 0; i < 4; i++) af[i] = ldfrag(Ab, arow + i * 16, g);
#pragma unroll
    for (int i = 0; i < 4; i++) bf4[i] = ldfrag(Bb, brow + i * 16, g);
    asm volatile("s_waitcnt lgkmcnt(0)" ::: "memory");
    __builtin_amdgcn_s_barrier();
    if (t + 2 < nkt) {
      stage16k(A, D_, m0, (t + 2) * 32, (char*)As[b], tid);
      stage8k(Bt, D_, n0, (t + 2) * 32, (char*)Bs[b], tid);
    }
    __builtin_amdgcn_s_setprio(1);
#pragma unroll
    for (int m = 0; m < 4; m++)
#pragma unroll
      for (int n = 0; n < 4; n++) acc[m][n] = mfma_bf16(af[m], bf4[n], acc[m][n]);
    __builtin_amdgcn_s_setprio(0);
  }
#pragma unroll
  for (int m = 0; m < 4; m++)
#pragma unroll
    for (int n = 0; n < 4; n++)
#pragma unroll
      for (int r = 0; r < 4; r++) {
        int row = m0 + wm * 64 + m * 16 + (g << 2) + r;
        int col = n0 + wn * 64 + n * 16 + lr;
        float bias = (col < D_) ? bq[col] : ((col < 2 * D_) ? bk[col - D_] : bv[col - 2 * D_]);
        C[(size_t)row * D3_ + col] = f2bf(acc[m][n][r] + bias);
      }
}

// ---------- K11: fused gate/up GEMM, 256x(128+128) tile, 8 waves, silu*mul ----------
__global__ __launch_bounds__(512, 2) void k_gemm_gup8(const unsigned short* __restrict__ A,
    const unsigned short* __restrict__ Bg, const unsigned short* __restrict__ Bu,
    unsigned short* __restrict__ act) {
  alignas(16) __shared__ short As[2][256 * 32];
  alignas(16) __shared__ short Bgs[2][128 * 32];
  alignas(16) __shared__ short Bus[2][128 * 32];
  int tid = threadIdx.x;
  int lane = tid & 63, g = lane >> 4, lr = lane & 15;
  int wid = tid >> 6, wm = wid >> 1, wn = wid & 1;
  int m0 = blockIdx.x * 256, n0 = blockIdx.y * 128;
  f32x4 zero4 = {0.f, 0.f, 0.f, 0.f};
  f32x4 ag[4][4], au[4][4];
#pragma unroll
  for (int m = 0; m < 4; m++)
#pragma unroll
    for (int n = 0; n < 4; n++) { ag[m][n] = zero4; au[m][n] = zero4; }
  const int nkt = D_ / 32;
  stage16k(A, D_, m0, 0, (char*)As[0], tid);
  stage8k(Bg, D_, n0, 0, (char*)Bgs[0], tid);
  stage8k(Bu, D_, n0, 0, (char*)Bus[0], tid);
  stage16k(A, D_, m0, 32, (char*)As[1], tid);
  stage8k(Bg, D_, n0, 32, (char*)Bgs[1], tid);
  stage8k(Bu, D_, n0, 32, (char*)Bus[1], tid);
  int arow = wm * 64 + lr;
  int brow = wn * 64 + lr;
  for (int t = 0; t < nkt; t++) {
    int b = t & 1;
    const char* Ab = (const char*)As[b];
    const char* Bgb = (const char*)Bgs[b];
    const char* Bub = (const char*)Bus[b];
    if (t + 1 < nkt) asm volatile("s_waitcnt vmcnt(4)" ::: "memory");
    else             asm volatile("s_waitcnt vmcnt(0)" ::: "memory");
    __builtin_amdgcn_s_barrier();
    s16x8 af[4], bg4[4], bu4[4];
#pragma unroll
    for (int i = 0; i < 4; i++) af[i] = ldfrag(Ab, arow + i * 16, g);
#pragma unroll
    for (int i = 0; i < 4; i++) bg4[i] = ldfrag(Bgb, brow + i * 16, g);
#pragma unroll
    for (int i = 0; i < 4; i++) bu4[i] = ldfrag(Bub, brow + i * 16, g);
    asm volatile("s_waitcnt lgkmcnt(0)" ::: "memory");
    __builtin_amdgcn_s_barrier();
    if (t + 2 < nkt) {
      stage16k(A, D_, m0, (t + 2) * 32, (char*)As[b], tid);
      stage8k(Bg, D_, n0, (t + 2) * 32, (char*)Bgs[b], tid);
      stage8k(Bu, D_, n0, (t + 2) * 32, (char*)Bus[b], tid);
    }
    __builtin_amdgcn_s_setprio(1);
#pragma unroll
    for (int m = 0; m < 4; m++)
#pragma unroll
      for (int n = 0; n < 4; n++) {
        ag[m][n] = mfma_bf16(af[m], bg4[n], ag[m][n]);
        au[m][n] = mfma_bf16(af[m], bu4[n], au[m][n]);
      }
    __builtin_amdgcn_s_setprio(0);
  }
#pragma unroll
  for (int m = 0; m < 4; m++)
#pragma unroll
    for (int n = 0; n < 4; n++)
#pragma unroll
      for (int r = 0; r < 4; r++) {
        int row = m0 + wm * 64 + m * 16 + (g << 2) + r;
        int col = n0 + wn * 64 + n * 16 + lr;
        float gv = ag[m][n][r], uv = au[m][n][r];
        float si = gv / (1.f + __expf(-gv));
        act[(size_t)row * I_ + col] = f2bf(si * uv);
      }
}

// ---------- K9: wo GEMM + residual, 64x128 tile, 4 waves ----------
__global__ __launch_bounds__(256, 2) void k_gemm_wo64(const unsigned short* __restrict__ A,
    const unsigned short* __restrict__ Bt, const float* __restrict__ xres,
    float* __restrict__ x1) {
  alignas(16) __shared__ short As[2][64 * 32];
  alignas(16) __shared__ short Bs[2][128 * 32];
  int tid = threadIdx.x;
  int lane = tid & 63, g = lane >> 4, lr = lane & 15, wid = tid >> 6;
  int m0 = blockIdx.x * 64, n0 = blockIdx.y * 128;
  f32x4 zero4 = {0.f, 0.f, 0.f, 0.f};
  f32x4 acc[4][2];
#pragma unroll
  for (int m = 0; m < 4; m++)
#pragma unroll
    for (int n = 0; n < 2; n++) acc[m][n] = zero4;
  const int nkt = D_ / 32;
  stage64r(A, D_, m0, 0, (char*)As[0], tid);
  stage128r(Bt, D_, n0, 0, (char*)Bs[0], tid);
  stage64r(A, D_, m0, 32, (char*)As[1], tid);
  stage128r(Bt, D_, n0, 32, (char*)Bs[1], tid);
  for (int t = 0; t < nkt; t++) {
    int b = t & 1;
    const char* Ab = (const char*)As[b];
    const char* Bb = (const char*)Bs[b];
    if (t + 1 < nkt) asm volatile("s_waitcnt vmcnt(3)" ::: "memory");
    else             asm volatile("s_waitcnt vmcnt(0)" ::: "memory");
    __builtin_amdgcn_s_barrier();
    s16x8 af[4], bf2[2];
#pragma unroll
    for (int i = 0; i < 4; i++) af[i] = ldfrag(Ab, i * 16 + lr, g);
#pragma unroll
    for (int j = 0; j < 2; j++) bf2[j] = ldfrag(Bb, wid * 32 + j * 16 + lr, g);
    asm volatile("s_waitcnt lgkmcnt(0)" ::: "memory");
    __builtin_amdgcn_s_barrier();
    if (t + 2 < nkt) {
      stage64r(A, D_, m0, (t + 2) * 32, (char*)As[b], tid);
      stage128r(Bt, D_, n0, (t + 2) * 32, (char*)Bs[b], tid);
    }
    __builtin_amdgcn_s_setprio(1);
#pragma unroll
    for (int m = 0; m < 4; m++)
#pragma unroll
      for (int n = 0; n < 2; n++) acc[m][n] = mfma_bf16(af[m], bf2[n], acc[m][n]);
    __builtin_amdgcn_s_setprio(0);
  }
#pragma unroll
  for (int m = 0; m < 4; m++)
#pragma unroll
    for (int n = 0; n < 2; n++)
#pragma unroll
      for (int r = 0; r < 4; r++) {
        int row = m0 + m * 16 + (g << 2) + r;
        int col = n0 + wid * 32 + n * 16 + lr;
        x1[(size_t)row * D_ + col] = acc[m][n][r] + xres[(size_t)row * D_ + col];
      }
}

// ---------- K12: down GEMM + residual + blend + scatter, 64x128 tile ----------
__global__ __launch_bounds__(256, 2) void k_gemm_down64(const unsigned short* __restrict__ A,
    const unsigned short* __restrict__ Bt, const float* __restrict__ x1,
    const float* __restrict__ x, const float* __restrict__ gate,
    const int* __restrict__ pos, float* __restrict__ out) {
  alignas(16) __shared__ short As[2][64 * 32];
  alignas(16) __shared__ short Bs[2][128 * 32];
  int tid = threadIdx.x;
  int lane = tid & 63, g = lane >> 4, lr = lane & 15, wid = tid >> 6;
  int m0 = blockIdx.x * 64, n0 = blockIdx.y * 128;
  f32x4 zero4 = {0.f, 0.f, 0.f, 0.f};
  f32x4 acc[4][2];
#pragma unroll
  for (int m = 0; m < 4; m++)
#pragma unroll
    for (int n = 0; n < 2; n++) acc[m][n] = zero4;
  const int nkt = I_ / 32;
  stage64r(A, I_, m0, 0, (char*)As[0], tid);
  stage128r(Bt, I_, n0, 0, (char*)Bs[0], tid);
  stage64r(A, I_, m0, 32, (char*)As[1], tid);
  stage128r(Bt, I_, n0, 32, (char*)Bs[1], tid);
  for (int t = 0; t < nkt; t++) {
    int b = t & 1;
    const char* Ab = (const char*)As[b];
    const char* Bb = (const char*)Bs[b];
    if (t + 1 < nkt) asm volatile("s_waitcnt vmcnt(3)" ::: "memory");
    else             asm volatile("s_waitcnt vmcnt(0)" ::: "memory");
    __builtin_amdgcn_s_barrier();
    s16x8 af[4], bf2[2];
#pragma unroll
    for (int i = 0; i < 4; i++) af[i] = ldfrag(Ab, i * 16 + lr, g);
#pragma unroll
    for (int j = 0; j < 2; j++) bf2[j] = ldfrag(Bb, wid * 32 + j * 16 + lr, g);
    asm volatile("s_waitcnt lgkmcnt(0)" ::: "memory");
    __builtin_amdgcn_s_barrier();
    if (t + 2 < nkt) {
      stage64r(A, I_, m0, (t + 2) * 32, (char*)As[b], tid);
      stage128r(Bt, I_, n0, (t + 2) * 32, (char*)Bs[b], tid);
    }
    __builtin_amdgcn_s_setprio(1);
#pragma unroll
    for (int m = 0; m < 4; m++)
#pragma unroll
      for (int n = 0; n < 2; n++) acc[m][n] = mfma_bf16(af[m], bf2[n], acc[m][n]);
    __builtin_amdgcn_s_setprio(0);
  }
#pragma unroll
  for (int m = 0; m < 4; m++)
#pragma unroll
    for (int n = 0; n < 2; n++)
#pragma unroll
      for (int r = 0; r < 4; r++) {
        int srow = m0 + m * 16 + (g << 2) + r;
        int col = n0 + wid * 32 + n * 16 + lr;
        float proc = acc[m][n][r] + x1[(size_t)srow * D_ + col];
        float gt = gate[srow];
        float xv = x[(size_t)srow * D_ + col];
        int bb = srow >> 9;
        int p = pos[srow];
        out[((size_t)bb * T_ + p) * D_ + col] = gt * proc + (1.f - gt) * xv;
      }
}

// ---------- K7: RoPE + head relayout (q,k row-major per head; v transposed) ----------
__global__ __launch_bounds__(256) void k_rope(const unsigned short* __restrict__ qkv,
    const float* __restrict__ cosb, const float* __restrict__ sinb,
    unsigned short* __restrict__ qh, unsigned short* __restrict__ kh,
    unsigned short* __restrict__ vT) {
  int s0 = blockIdx.x * 64;
  int h = blockIdx.y;
  int t = threadIdx.x;
#pragma unroll
  for (int i = 0; i < 16; i++) {
    int flat = t + i * 256;
    int r = flat >> 6, dp = flat & 63;
    int s = s0 + r;
    float c = cosb[s * 64 + dp], sn = sinb[s * 64 + dp];
    const unsigned short* qrow = qkv + (size_t)s * D3_ + h * HD_;
    float q1 = bf2f(qrow[dp]), q2 = bf2f(qrow[dp + 64]);
    unsigned short* qdst = qh + ((size_t)h * S_ + s) * HD_;
    qdst[dp] = f2bf(q1 * c - q2 * sn);
    qdst[dp + 64] = f2bf(q2 * c + q1 * sn);
    const unsigned short* krow = qrow + D_;
    float k1 = bf2f(krow[dp]), k2 = bf2f(krow[dp + 64]);
    unsigned short* kdst = kh + ((size_t)h * S_ + s) * HD_;
    kdst[dp] = f2bf(k1 * c - k2 * sn);
    kdst[dp + 64] = f2bf(k2 * c + k1 * sn);
  }
  __shared__ unsigned short vt[128][66];
#pragma unroll
  for (int i = 0; i < 32; i++) {
    int flat = t + i * 256;
    int r = flat >> 7, d = flat & 127;
    vt[d][r] = qkv[(size_t)(s0 + r) * D3_ + 2 * D_ + h * HD_ + d];
  }
  __syncthreads();
#pragma unroll
  for (int i = 0; i < 32; i++) {
    int flat = t + i * 256;
    int d = flat >> 6, sc = flat & 63;
    vT[((size_t)h * HD_ + d) * S_ + s0 + sc] = vt[d][sc];
  }
}

// ======================================================================
// K8: flash attention (q-tile 64, LPT order, swizzled LDS, dbuf KV)
// ======================================================================
__device__ __forceinline__ void stage_kv(const unsigned short* __restrict__ kh,
                                         const unsigned short* __restrict__ vT,
                                         size_t hbase, int kt, char* KsB, char* VsB, int tid) {
#pragma unroll
  for (int c = 0; c < 4; c++) {
    int off = c * 4096 + tid * 16;
    int row = off >> 8;
    int cb = (off & 255) ^ ((row & 7) << 4);
    gl_lds16(kh + hbase + (size_t)(kt * 64 + row) * HD_ + (cb >> 1), KsB + off);
  }
#pragma unroll
  for (int c = 0; c < 4; c++) {
    int off = c * 4096 + tid * 16;
    int row = off >> 7;
    int cb = (off & 127) ^ ((row & 7) << 4);
    gl_lds16(vT + hbase + (size_t)row * S_ + kt * 64 + (cb >> 1), VsB + off);
  }
}

__global__ __launch_bounds__(256, 2) void k_attn(const unsigned short* __restrict__ qh,
                                                 const unsigned short* __restrict__ kh,
                                                 const unsigned short* __restrict__ vT,
                                                 unsigned short* __restrict__ ao) {
  alignas(16) __shared__ short Ks[2][64 * 128];   // [kv][d], 256B rows, swizzled
  alignas(16) __shared__ short Vs[2][128 * 64];   // [d][kv], 128B rows, swizzled
  alignas(16) __shared__ short Ps[4][16 * 64];    // per-wave P, 128B rows, swizzled
  int bidx = blockIdx.x;
  int head = bidx & 15;
  int slot = bidx >> 4;                      // 0..31
  int qt = (slot < 16) ? (31 - slot) : (slot - 16);
  int q0 = qt * 64;
  int tid = threadIdx.x, w = tid >> 6, lane = tid & 63, g = lane >> 4, lr = lane & 15;
  size_t hbase = (size_t)head * S_ * HD_;
  int qw = q0 + w * 16;
  char* PsW = (char*)&Ps[w][0];
  s16x8 qf[4];
#pragma unroll
  for (int ks = 0; ks < 4; ks++)
    qf[ks] = *(const s16x8*)&qh[hbase + (size_t)(qw + lr) * HD_ + ks * 32 + g * 8];
  f32x4 o[8];
  f32x4 zero4 = {0.f, 0.f, 0.f, 0.f};
#pragma unroll
  for (int nf = 0; nf < 8; nf++) o[nf] = zero4;
  float m_i[4], l_i[4];
#pragma unroll
  for (int r = 0; r < 4; r++) { m_i[r] = -1e30f; l_i[r] = 0.f; }
  const float sc = 0.08838834764831843f;  // 1/sqrt(128)

  stage_kv(kh, vT, hbase, 0, (char*)Ks[0], (char*)Vs[0], tid);
  if (qt > 0) stage_kv(kh, vT, hbase, 1, (char*)Ks[1], (char*)Vs[1], tid);

  for (int kt = 0; kt <= qt; kt++) {
    int b = kt & 1;
    const char* KsB = (const char*)Ks[b];
    const char* VsB = (const char*)Vs[b];
    if (kt < qt) asm volatile("s_waitcnt vmcnt(8)" ::: "memory");
    else         asm volatile("s_waitcnt vmcnt(0)" ::: "memory");
    __builtin_amdgcn_s_barrier();
    f32x4 sacc[4];
#pragma unroll
    for (int nf = 0; nf < 4; nf++) sacc[nf] = zero4;
#pragma unroll
    for (int ks = 0; ks < 4; ks++) {
      s16x8 kf[4];
#pragma unroll
      for (int nf = 0; nf < 4; nf++) {
        int row = nf * 16 + lr;
        kf[nf] = *(const s16x8*)(KsB + row * 256 + (((ks << 6) + (g << 4)) ^ ((row & 7) << 4)));
      }
#pragma unroll
      for (int nf = 0; nf < 4; nf++) sacc[nf] = mfma_bf16(qf[ks], kf[nf], sacc[nf]);
    }
    bool diag = (kt == qt);
#pragma unroll
    for (int r = 0; r < 4; r++) {
      int prow = (g << 2) + r;
      int qrow = qw + prow;
      float pv[4];
      float mx = -1e30f;
#pragma unroll
      for (int nf = 0; nf < 4; nf++) {
        float vv = sacc[nf][r] * sc;
        if (diag) {
          int kc = kt * 64 + nf * 16 + lr;
          vv = (kc <= qrow) ? vv : -1e30f;
        }
        pv[nf] = vv;
        mx = fmaxf(mx, vv);
      }
#pragma unroll
      for (int d = 1; d < 16; d <<= 1) mx = fmaxf(mx, __shfl_xor(mx, d));
      float mold = m_i[r], mnew = fmaxf(mold, mx);
      float corr = __expf(mold - mnew);
      float ssum = 0.f;
#pragma unroll
      for (int nf = 0; nf < 4; nf++) {
        float pe = __expf(pv[nf] - mnew);
        int cb = ((nf * 16 + lr) << 1) ^ ((prow & 7) << 4);
        *(unsigned short*)(PsW + prow * 128 + cb) = f2bf(pe);
        ssum += pe;
      }
#pragma unroll
      for (int d = 1; d < 16; d <<= 1) ssum += __shfl_xor(ssum, d);
      l_i[r] = l_i[r] * corr + ssum;
      m_i[r] = mnew;
#pragma unroll
      for (int nf = 0; nf < 8; nf++) o[nf][r] *= corr;
    }
    s16x8 pa[2];
#pragma unroll
    for (int ks = 0; ks < 2; ks++)
      pa[ks] = *(const s16x8*)(PsW + lr * 128 + (((ks << 6) + (g << 4)) ^ ((lr & 7) << 4)));
#pragma unroll
    for (int nf = 0; nf < 8; nf++) {
#pragma unroll
      for (int ks = 0; ks < 2; ks++) {
        int row = nf * 16 + lr;
        s16x8 vb = *(const s16x8*)(VsB + row * 128 + (((ks << 6) + (g << 4)) ^ ((row & 7) << 4)));
        o[nf] = mfma_bf16(pa[ks], vb, o[nf]);
      }
    }
    asm volatile("s_waitcnt lgkmcnt(0)" ::: "memory");
    __builtin_amdgcn_s_barrier();
    if (kt + 2 <= qt)
      stage_kv(kh, vT, hbase, kt + 2, (char*)Ks[b], (char*)Vs[b], tid);
  }
#pragma unroll
  for (int nf = 0; nf < 8; nf++)
#pragma unroll
    for (int r = 0; r < 4; r++) {
      int row = qw + (g << 2) + r;
      int col = head * HD_ + nf * 16 + lr;
      ao[(size_t)row * D_ + col] = f2bf(o[nf][r] / l_i[r]);
    }
}

// ---------- K10: RMS2 ----------
__global__ __launch_bounds__(256) void k_rms2(const float* __restrict__ x1,
                                              const float* __restrict__ ln2w,
                                              unsigned short* __restrict__ xn2) {
  int s = blockIdx.x, t = threadIdx.x;
  const float* src = x1 + (size_t)s * D_;
  float v[8];
  float ss = 0.f;
#pragma unroll
  for (int i = 0; i < 8; i++) { v[i] = src[t + i * 256]; ss += v[i] * v[i]; }
  __shared__ float red[4];
#pragma unroll
  for (int d = 32; d; d >>= 1) ss += __shfl_xor(ss, d);
  if ((t & 63) == 0) red[t >> 6] = ss;
  __syncthreads();
  ss = red[0] + red[1] + red[2] + red[3];
  float scale = rsqrtf(ss / (float)D_ + 1e-6f);
  unsigned short* dst = xn2 + (size_t)s * D_;
#pragma unroll
  for (int i = 0; i < 8; i++) {
    int c = t + i * 256;
    dst[c] = f2bf(v[i] * scale * ln2w[c]);
  }
}

extern "C" void kernel_launch(void* const* d_in, const int* in_sizes, int n_in,
                              void* d_out, int out_size, void* d_ws, size_t ws_size,
                              hipStream_t stream) {
  (void)in_sizes; (void)n_in; (void)out_size; (void)ws_size;
  const float* hidden = (const float*)d_in[0];
  const float* router_w = (const float*)d_in[1];
  const float* router_b = (const float*)d_in[2];
  const float* ln1w = (const float*)d_in[3];
  const float* ln2w = (const float*)d_in[4];
  const float* wq = (const float*)d_in[5];
  const float* bq = (const float*)d_in[6];
  const float* wk = (const float*)d_in[7];
  const float* bk = (const float*)d_in[8];
  const float* wv = (const float*)d_in[9];
  const float* bv = (const float*)d_in[10];
  const float* wo = (const float*)d_in[11];
  const float* wg = (const float*)d_in[12];
  const float* wu = (const float*)d_in[13];
  const float* wd = (const float*)d_in[14];
  float* out = (float*)d_out;

  char* ws = (char*)d_ws;
  size_t off = 0;
  auto alloc = [&](size_t bytes) {
    char* p = ws + off;
    off += (bytes + 255) & ~(size_t)255;
    return p;
  };
  unsigned short* wqkvT = (unsigned short*)alloc(3ull * D_ * D_ * 2);
  unsigned short* woT = (unsigned short*)alloc((size_t)D_ * D_ * 2);
  unsigned short* wgT = (unsigned short*)alloc((size_t)I_ * D_ * 2);
  unsigned short* wuT = (unsigned short*)alloc((size_t)I_ * D_ * 2);
  unsigned short* wdT = (unsigned short*)alloc((size_t)D_ * I_ * 2);
  float* scores = (float*)alloc((size_t)B_ * T_ * 4);
  int* pos = (int*)alloc((size_t)S_ * 4);
  float* gate = (float*)alloc((size_t)S_ * 4);
  float* x = (float*)alloc((size_t)S_ * D_ * 4);
  float* x1 = (float*)alloc((size_t)S_ * D_ * 4);
  unsigned short* xn = (unsigned short*)alloc((size_t)S_ * D_ * 2);  // reused as x1n
  float* cosb = (float*)alloc((size_t)S_ * 64 * 4);
  float* sinb = (float*)alloc((size_t)S_ * 64 * 4);
  unsigned short* qkv = (unsigned short*)alloc((size_t)S_ * D3_ * 2);  // reused as act
  unsigned short* qh = (unsigned short*)alloc((size_t)H_ * S_ * HD_ * 2);
  unsigned short* kh = (unsigned short*)alloc((size_t)H_ * S_ * HD_ * 2);
  unsigned short* vT = (unsigned short*)alloc((size_t)H_ * S_ * HD_ * 2);
  unsigned short* ao = (unsigned short*)alloc((size_t)S_ * D_ * 2);

  k_copy_scores<<<B_ * T_, 256, 0, stream>>>((const float4*)hidden, (float4*)out,
                                             (const float4*)router_w, router_b, scores);

  k_transpose<<<dim3(D_ / 32, D_ / 32), 256, 0, stream>>>(wq, wqkvT, D_, D_);
  k_transpose<<<dim3(D_ / 32, D_ / 32), 256, 0, stream>>>(wk, wqkvT + (size_t)D_ * D_, D_, D_);
  k_transpose<<<dim3(D_ / 32, D_ / 32), 256, 0, stream>>>(wv, wqkvT + 2ull * D_ * D_, D_, D_);
  k_transpose<<<dim3(D_ / 32, D_ / 32), 256, 0, stream>>>(wo, woT, D_, D_);
  k_transpose<<<dim3(I_ / 32, D_ / 32), 256, 0, stream>>>(wg, wgT, D_, I_);
  k_transpose<<<dim3(I_ / 32, D_ / 32), 256, 0, stream>>>(wu, wuT, D_, I_);
  k_transpose<<<dim3(D_ / 32, I_ / 32), 256, 0, stream>>>(wd, wdT, I_, D_);

  k_topk<<<B_, 1024, 0, stream>>>(scores, pos);
  k_gather<<<S_, 256, 0, stream>>>(hidden, pos, scores, ln1w, x, xn, gate, cosb, sinb);

  k_gemm_qkv8<<<dim3(S_ / 256, D3_ / 128), 512, 0, stream>>>(xn, wqkvT, qkv, bq, bk, bv);
  k_rope<<<dim3(S_ / 64, H_), 256, 0, stream>>>(qkv, cosb, sinb, qh, kh, vT);
  k_attn<<<32 * H_, 256, 0, stream>>>(qh, kh, vT, ao);
  k_gemm_wo64<<<dim3(S_ / 64, D_ / 128), 256, 0, stream>>>(ao, woT, x, x1);
  k_rms2<<<S_, 256, 0, stream>>>(x1, ln2w, xn);
  k_gemm_gup8<<<dim3(S_ / 256, I_ / 128), 512, 0, stream>>>(xn, wgT, wuT, qkv);
  k_gemm_down64<<<dim3(S_ / 64, D_ / 128), 256, 0, stream>>>(qkv, wdT, x1, x, gate, pos, out);
}